// Round 1
// baseline (1663.970 us; speedup 1.0000x reference)
//
#include <hip/hip_runtime.h>
#include <stdint.h>

// ---------------- constants ----------------
namespace {
constexpr int B_ = 128;
constexpr int L_ = 50;
constexpr int D_ = 128;
constexpr int S_ = 8;
constexpr int NSC_ = 99999;       // NUM_NODE-1
constexpr int NBR_ = 9;
}
#define LEAKY_ 0.2f
#define BETA_ 0.005f

__device__ __forceinline__ float leaky_(float x){ return x >= 0.f ? x : LEAKY_*x; }
__device__ __forceinline__ float sigm_(float x){ return 1.f/(1.f+expf(-x)); }

// ---------------- threefry2x32 (JAX-compatible) ----------------
__device__ __forceinline__ void tf2x32(uint32_t k0, uint32_t k1, uint32_t c0, uint32_t c1,
                                       uint32_t* o0, uint32_t* o1){
  uint32_t ks2 = k0 ^ k1 ^ 0x1BD11BDAu;
  uint32_t x0 = c0 + k0, x1 = c1 + k1;
#define RND_(r) { x0 += x1; x1 = (x1<<(r))|(x1>>(32-(r))); x1 ^= x0; }
  RND_(13) RND_(15) RND_(26) RND_(6)   x0 += k1;  x1 += ks2 + 1u;
  RND_(17) RND_(29) RND_(16) RND_(24)  x0 += ks2; x1 += k0  + 2u;
  RND_(13) RND_(15) RND_(26) RND_(6)   x0 += k0;  x1 += k1  + 3u;
  RND_(17) RND_(29) RND_(16) RND_(24)  x0 += k1;  x1 += ks2 + 4u;
  RND_(13) RND_(15) RND_(26) RND_(6)   x0 += ks2; x1 += k0  + 5u;
#undef RND_
  *o0 = x0; *o1 = x1;
}

// ---------------- K1: h = embedding[inputs] ----------------
__global__ void k_gather_h(const int* __restrict__ inputs, const float* __restrict__ emb,
                           float* __restrict__ h){
  int p = blockIdx.x, t = threadIdx.x;
  h[(size_t)p*D_ + t] = emb[(size_t)inputs[p]*D_ + t];
}

// ---------------- K2: sess = mean of masked item embeddings ----------------
__global__ void k_sess(const int* __restrict__ item, const int* __restrict__ mask,
                       const float* __restrict__ emb, float* __restrict__ sess){
  int b = blockIdx.x, t = threadIdx.x;
  float acc = 0.f, ms = 0.f;
  for (int l = 0; l < L_; l++){
    float mk = (float)mask[b*L_ + l];
    ms += mk;
    acc += mk * emb[(size_t)item[b*L_ + l]*D_ + t];
  }
  sess[(size_t)b*D_ + t] = acc / ms;
}

// ---------------- K3: local GAT aggregation ----------------
__global__ __launch_bounds__(256) void k_local(const float* __restrict__ h,
                                               const int* __restrict__ adj,
                                               const float* __restrict__ a_local,
                                               float* __restrict__ hl){
  __shared__ float hs[L_*129];   // +1 pad
  __shared__ float att[L_*52];
  __shared__ float al[4*132];
  int b = blockIdx.x, tid = threadIdx.x;
  for (int e = tid; e < L_*D_; e += 256){
    int i = e >> 7, d = e & 127;
    hs[i*129 + d] = h[((size_t)b*L_ + i)*D_ + d];
  }
  for (int e = tid; e < 4*D_; e += 256){
    al[(e>>7)*132 + (e&127)] = a_local[e];
  }
  __syncthreads();
  for (int p = tid; p < L_*L_; p += 256){
    int i = p / L_, j = p % L_;
    int k = adj[((size_t)b*L_ + i)*L_ + j];
    float v = -9e15f;
    if (k >= 1){
      const float* ak = &al[(k-1)*132];
      float acc = 0.f;
      for (int d = 0; d < D_; d++) acc += hs[i*129+d]*hs[j*129+d]*ak[d];
      v = leaky_(acc);
    }
    att[i*52 + j] = v;
  }
  __syncthreads();
  if (tid < L_){
    int i = tid;
    float mx = -INFINITY;
    for (int j = 0; j < L_; j++) mx = fmaxf(mx, att[i*52+j]);
    float sm = 0.f;
    for (int j = 0; j < L_; j++){ float e_ = expf(att[i*52+j] - mx); att[i*52+j] = e_; sm += e_; }
    float inv = 1.f/sm;
    for (int j = 0; j < L_; j++) att[i*52+j] *= inv;
  }
  __syncthreads();
  for (int q = tid; q < L_*D_; q += 256){
    int i = q >> 7, d = q & 127;
    float acc = 0.f;
    for (int j = 0; j < L_; j++) acc += att[i*52+j]*hs[j*129+d];
    hl[((size_t)b*L_ + i)*D_ + d] = acc;
  }
}

// ---------------- K4/K5: neighbor sampling ----------------
__global__ void k_sample(const int* __restrict__ src, const int* __restrict__ adj_all,
                         const float* __restrict__ num_w, int n,
                         int* __restrict__ out_i, float* __restrict__ out_w){
  int p = blockIdx.x*blockDim.x + threadIdx.x;
  if (p < n){
    int base = src[p >> 3];
    int off  = base*S_ + (p & 7);
    out_i[p] = adj_all[off];
    out_w[p] = num_w[off];
  }
}

// ---------------- K6a: global_agg attention -> neigh (in-place into out buffer) ----------------
__global__ __launch_bounds__(256) void k_gagg_att(const float* __restrict__ emb,
    const float* __restrict__ neigh_dense, const int* __restrict__ neigh_idx,
    const float* __restrict__ nw, const float* __restrict__ sess,
    const float* __restrict__ w1, const float* __restrict__ w2,
    float* __restrict__ out_neigh, int M, int MC)
{
  __shared__ __align__(16) float ws1[128*D_];  // sess[e]*w1[e][dd], 64 KB
  __shared__ __align__(16) float w1l[D_];      // w1 row 128
  __shared__ __align__(16) float w2s[D_];
  __shared__ float sesss[D_];
  __shared__ float nv[S_*D_];
  __shared__ float logits[S_];
  __shared__ float alpha[S_];
  int b = blockIdx.y;
  int tid = threadIdx.x;
  if (tid < D_){
    sesss[tid] = sess[(size_t)b*D_ + tid];
    w1l[tid]   = w1[128*D_ + tid];
    w2s[tid]   = w2[tid];
  }
  __syncthreads();
  for (int e = tid; e < 128*D_; e += 256) ws1[e] = w1[e]*sesss[e >> 7];
  __syncthreads();
  int s = tid >> 5, lane = tid & 31, dd4 = lane*4;
  int mend = min(blockIdx.x*MC + MC, M);
  for (int mm = blockIdx.x*MC; mm < mend; mm++){
    size_t rbase = ((size_t)b*M + mm)*S_;
    for (int e = tid; e < S_*D_; e += 256){
      int ss2 = e >> 7, d = e & 127;
      const float* row = neigh_dense ? (neigh_dense + (rbase + ss2)*D_)
                                     : (emb + (size_t)neigh_idx[rbase + ss2]*D_);
      nv[e] = row[d];
    }
    __syncthreads();
    float nws = nw[rbase + s];
    float a0, a1_, a2, a3;
    {
      const float4 wl4 = *reinterpret_cast<const float4*>(&w1l[dd4]);
      a0 = nws*wl4.x; a1_ = nws*wl4.y; a2 = nws*wl4.z; a3 = nws*wl4.w;
    }
    for (int e = 0; e < D_; e++){
      float nvv = nv[s*D_ + e];
      const float4 w4 = *reinterpret_cast<const float4*>(&ws1[e*D_ + dd4]);
      a0 += nvv*w4.x; a1_ += nvv*w4.y; a2 += nvv*w4.z; a3 += nvv*w4.w;
    }
    const float4 w24 = *reinterpret_cast<const float4*>(&w2s[dd4]);
    float contrib = leaky_(a0)*w24.x + leaky_(a1_)*w24.y + leaky_(a2)*w24.z + leaky_(a3)*w24.w;
    for (int off = 16; off >= 1; off >>= 1) contrib += __shfl_down(contrib, off, 32);
    if (lane == 0) logits[s] = contrib;
    __syncthreads();
    if (tid == 0){
      float mx = -INFINITY;
      for (int t2 = 0; t2 < S_; t2++) mx = fmaxf(mx, logits[t2]);
      float sm = 0.f;
      for (int t2 = 0; t2 < S_; t2++){ float e_ = expf(logits[t2]-mx); alpha[t2] = e_; sm += e_; }
      float inv = 1.f/sm;
      for (int t2 = 0; t2 < S_; t2++) alpha[t2] *= inv;
    }
    __syncthreads();
    if (tid < D_){
      float nh = 0.f;
#pragma unroll
      for (int t2 = 0; t2 < S_; t2++) nh += alpha[t2]*nv[t2*D_ + tid];
      out_neigh[((size_t)b*M + mm)*D_ + tid] = nh;
    }
    __syncthreads();
  }
}

// ---------------- K6b: out = relu([self, neigh] @ w3), in-place over neigh buffer ----------------
__global__ __launch_bounds__(256) void k_gagg_out(const float* __restrict__ emb,
    const float* __restrict__ self_dense, const int* __restrict__ self_idx,
    const float* __restrict__ w3, float* __restrict__ inout, int nrows, int rpb)
{
  __shared__ __align__(16) float w3s[256*D_];  // 131 KB
  __shared__ float crow[256];
  __shared__ __align__(16) float red[8*D_];
  int tid = threadIdx.x;
  for (int e = tid; e < 256*D_; e += 256) w3s[e] = w3[e];
  __syncthreads();
  int r0 = blockIdx.x * rpb;
  int r1 = min(r0 + rpb, nrows);
  int g = tid >> 5, lane = tid & 31, dd4 = lane*4;
  for (int r = r0; r < r1; r++){
    if (tid < D_){
      const float* srow = self_dense ? (self_dense + (size_t)r*D_)
                                     : (emb + (size_t)self_idx[r]*D_);
      crow[tid]      = srow[tid];
      crow[D_ + tid] = inout[(size_t)r*D_ + tid];
    }
    __syncthreads();
    float a0 = 0.f, a1 = 0.f, a2 = 0.f, a3 = 0.f;
#pragma unroll 4
    for (int e2 = 0; e2 < 32; e2++){
      int e = g*32 + e2;
      float c = crow[e];
      const float4 w4 = *reinterpret_cast<const float4*>(&w3s[e*D_ + dd4]);
      a0 += c*w4.x; a1 += c*w4.y; a2 += c*w4.z; a3 += c*w4.w;
    }
    *reinterpret_cast<float4*>(&red[g*D_ + dd4]) = make_float4(a0, a1, a2, a3);
    __syncthreads();
    if (tid < D_){
      float v = 0.f;
#pragma unroll
      for (int gg = 0; gg < 8; gg++) v += red[gg*D_ + tid];
      inout[(size_t)r*D_ + tid] = fmaxf(v, 0.f);
    }
    __syncthreads();
  }
}

// ---------------- K7: output = hl + hg; zero loss slot ----------------
__global__ void k_addout(const float* __restrict__ hl, const float* __restrict__ hg,
                         float* __restrict__ out){
  int i = blockIdx.x*256 + threadIdx.x;
  if (i < B_*L_*D_) out[i] = hl[i] + hg[i];
  else if (i == B_*L_*D_) out[i] = 0.f;
}

// ---------------- K8: jax.random permutations (partitionable threefry) ----------------
__global__ void k_perms(int* __restrict__ pr, int* __restrict__ pc){
  __shared__ uint32_t keys[128];
  int tid = threadIdx.x;
  // key(42) = (0,42); split -> kr = tf(key,(0,0)), kc = tf(key,(0,1))
  uint32_t kr0, kr1, kc0, kc1, sk0, sk1, o0, o1;
  tf2x32(0u, 42u, 0u, 0u, &kr0, &kr1);
  tf2x32(0u, 42u, 0u, 1u, &kc0, &kc1);
  // perm over 128: subkey = second key of split(kr)
  tf2x32(kr0, kr1, 0u, 1u, &sk0, &sk1);
  tf2x32(sk0, sk1, 0u, (uint32_t)tid, &o0, &o1);
  keys[tid] = o0 ^ o1;
  __syncthreads();
  {
    uint32_t mk = keys[tid];
    int rank = 0;
    for (int j = 0; j < 128; j++){
      uint32_t kj = keys[j];
      rank += (kj < mk) || (kj == mk && j < tid);
    }
    pr[rank] = tid;
  }
  __syncthreads();
  // perm over 50
  tf2x32(kc0, kc1, 0u, 1u, &sk0, &sk1);
  if (tid < 50){
    tf2x32(sk0, sk1, 0u, (uint32_t)tid, &o0, &o1);
    keys[tid] = o0 ^ o1;
  }
  __syncthreads();
  if (tid < 50){
    uint32_t mk = keys[tid];
    int rank = 0;
    for (int j = 0; j < 50; j++){
      uint32_t kj = keys[j];
      rank += (kj < mk) || (kj == mk && j < tid);
    }
    pc[rank] = tid;
  }
}

// ---------------- K9: SSL loss ----------------
__global__ void k_ssl(const float* __restrict__ hl, const float* __restrict__ hg,
                      const int* __restrict__ pr, const int* __restrict__ pc,
                      float* __restrict__ out_loss){
  __shared__ float red[128];
  int b = blockIdx.x, d = threadIdx.x;
  int prb = pr[b];
  float pos = 0.f, neg = 0.f;
  for (int l = 0; l < L_; l++){
    float hgv = hg[((size_t)b*L_ + l)*D_ + d];
    pos += hl[((size_t)b*L_ + l)*D_ + d] * hgv;
    neg += hgv * hl[((size_t)prb*L_ + pc[l])*D_ + d];
  }
  float term = -logf(1e-8f + sigm_(pos)) - logf(1e-8f + 1.f - sigm_(neg));
  red[d] = term;
  __syncthreads();
  for (int off = 64; off >= 1; off >>= 1){
    if (d < off) red[d] += red[d + off];
    __syncthreads();
  }
  if (d == 0) atomicAdd(out_loss, BETA_*red[0]);
}

// ---------------- K10: hs then g2 = hs @ glu2_w.T ----------------
__global__ void k_hs(const float* __restrict__ hidden, const int* __restrict__ mask,
                     const float* __restrict__ glu2_w, float* __restrict__ g2){
  __shared__ float hss[D_];
  int b = blockIdx.x, t = threadIdx.x;
  float acc = 0.f, ms = 0.f;
  for (int l = 0; l < L_; l++){
    float mk = (float)mask[b*L_ + l];
    ms += mk;
    acc += mk * hidden[((size_t)b*L_ + l)*D_ + t];
  }
  hss[t] = acc / ms;
  __syncthreads();
  float g = 0.f;
  for (int e = 0; e < D_; e++) g += hss[e]*glu2_w[t*D_ + e];
  g2[(size_t)b*D_ + t] = g;
}

// ---------------- K11: GLU gate -> select + norm ----------------
__global__ __launch_bounds__(128) void k_select(const float* __restrict__ hidden,
    const int* __restrict__ mask, const float* __restrict__ pos_emb,
    const float* __restrict__ w1, const float* __restrict__ w2,
    const float* __restrict__ glu1_w, const float* __restrict__ glu1_b,
    const float* __restrict__ g2, float* __restrict__ select, float* __restrict__ norms)
{
  __shared__ float hrow[D_], prow[D_], nh[D_], red[128];
  int b = blockIdx.x, t = threadIdx.x;
  float sel = 0.f;
  float g2v = g2[(size_t)b*D_ + t];
  float b1  = glu1_b[t];
  float w2t = w2[t];
  for (int l = 0; l < L_; l++){
    hrow[t] = hidden[((size_t)b*L_ + l)*D_ + t];
    prow[t] = pos_emb[l*D_ + t];
    __syncthreads();
    float acc = 0.f;
    for (int e = 0; e < D_; e++) acc += prow[e]*w1[e*D_ + t];
    for (int e = 0; e < D_; e++) acc += hrow[e]*w1[(D_+e)*D_ + t];
    nh[t] = tanhf(acc);
    __syncthreads();
    float a2 = 0.f;
    for (int e = 0; e < D_; e++) a2 += nh[e]*glu1_w[t*D_ + e];
    float ns = sigm_(a2 + b1 + g2v);
    red[t] = ns * w2t;
    __syncthreads();
    for (int off = 64; off >= 1; off >>= 1){
      if (t < off) red[t] += red[t + off];
      __syncthreads();
    }
    float beta = red[0] * (float)mask[b*L_ + l];
    sel += beta * hrow[t];
    __syncthreads();
  }
  select[(size_t)b*D_ + t] = sel;
  red[t] = sel*sel + 1e-6f;
  __syncthreads();
  for (int off = 64; off >= 1; off >>= 1){
    if (t < off) red[t] += red[t + off];
    __syncthreads();
  }
  if (t == 0) norms[b] = sqrtf(red[0]);
}

// ---------------- K12: cosine softmax + top-9 + neighbor mix ----------------
__global__ __launch_bounds__(128) void k_topk(const float* __restrict__ select,
                                              const float* __restrict__ norms,
                                              float* __restrict__ select2){
  __shared__ float p[B_];
  __shared__ float red[128];
  __shared__ float tv[NBR_];
  __shared__ int   ti[NBR_];
  int b = blockIdx.x, t = threadIdx.x;
  float dot = 0.f;
  for (int d = 0; d < D_; d++) dot += select[(size_t)b*D_ + d]*select[(size_t)t*D_ + d];
  float logit = dot / (norms[b]*norms[t]);
  red[t] = logit; __syncthreads();
  for (int off = 64; off >= 1; off >>= 1){
    if (t < off) red[t] = fmaxf(red[t], red[t + off]);
    __syncthreads();
  }
  float mx = red[0]; __syncthreads();
  float e_ = expf(logit - mx);
  red[t] = e_; __syncthreads();
  for (int off = 64; off >= 1; off >>= 1){
    if (t < off) red[t] += red[t + off];
    __syncthreads();
  }
  p[t] = e_ / red[0];
  __syncthreads();
  if (t == 0){
    unsigned long long used0 = 0ull, used1 = 0ull;
    for (int k = 0; k < NBR_; k++){
      float best = -INFINITY; int bi = 0;
      for (int j = 0; j < B_; j++){
        bool u = (j < 64) ? ((used0 >> j) & 1ull) : ((used1 >> (j-64)) & 1ull);
        if (!u && p[j] > best){ best = p[j]; bi = j; }
      }
      if (bi < 64) used0 |= 1ull << bi; else used1 |= 1ull << (bi-64);
      tv[k] = best; ti[k] = bi;
    }
    float mx2 = -INFINITY;
    for (int k = 0; k < NBR_; k++) mx2 = fmaxf(mx2, tv[k]);
    float s2 = 0.f;
    for (int k = 0; k < NBR_; k++){ tv[k] = expf(tv[k]-mx2); s2 += tv[k]; }
    for (int k = 0; k < NBR_; k++) tv[k] /= s2;
  }
  __syncthreads();
  float nb = 0.f;
#pragma unroll
  for (int k = 0; k < NBR_; k++) nb += tv[k]*select[(size_t)ti[k]*D_ + t];
  select2[(size_t)b*D_ + t] = select[(size_t)b*D_ + t] + nb;
}

// ---------------- K13: scores = select2 @ embedding[1:].T ----------------
__global__ __launch_bounds__(256) void k_scores(const float* __restrict__ sel2,
                                                const float* __restrict__ emb,
                                                float* __restrict__ scores){
  __shared__ float ss[64*129];
  __shared__ float et[32*129];
  int tid = threadIdx.x;
  int b0 = blockIdx.y * 64;
  int n0 = blockIdx.x * 32;
  for (int e = tid; e < 64*D_; e += 256){
    int bb = e >> 7, d = e & 127;
    ss[bb*129 + d] = sel2[(size_t)(b0 + bb)*D_ + d];
  }
  for (int e = tid; e < 32*D_; e += 256){
    int ni = e >> 7, d = e & 127;
    int n = n0 + ni;
    et[ni*129 + d] = (n < NSC_) ? emb[(size_t)(1 + n)*D_ + d] : 0.f;
  }
  __syncthreads();
  int ni = tid & 31, bg = tid >> 5;
  int n = n0 + ni;
  if (n < NSC_){
    float acc[8];
#pragma unroll
    for (int k = 0; k < 8; k++) acc[k] = 0.f;
    const float* ssp = &ss[bg*8*129];
    const float* etp = &et[ni*129];
    for (int d = 0; d < D_; d++){
      float ev = etp[d];
#pragma unroll
      for (int k = 0; k < 8; k++) acc[k] += ev*ssp[k*129 + d];
    }
#pragma unroll
    for (int k = 0; k < 8; k++)
      scores[(size_t)(b0 + bg*8 + k)*NSC_ + n] = acc[k];
  }
}

// ---------------- launcher ----------------
extern "C" void kernel_launch(void* const* d_in, const int* in_sizes, int n_in,
                              void* d_out, int out_size, void* d_ws, size_t ws_size,
                              hipStream_t stream) {
  (void)in_sizes; (void)n_in; (void)out_size; (void)ws_size;
  const int*   inputs  = (const int*)  d_in[0];
  const int*   adj     = (const int*)  d_in[1];
  const int*   mask    = (const int*)  d_in[2];
  const int*   item    = (const int*)  d_in[3];
  const int*   adj_all = (const int*)  d_in[5];
  const float* num_w   = (const float*)d_in[6];
  const float* emb     = (const float*)d_in[7];
  const float* pose    = (const float*)d_in[8];
  const float* a_local = (const float*)d_in[9];
  const float* gw1     = (const float*)d_in[10];
  const float* gw2     = (const float*)d_in[11];
  const float* gw3     = (const float*)d_in[12];
  const float* w1      = (const float*)d_in[13];
  const float* w2      = (const float*)d_in[14];
  const float* glu1w   = (const float*)d_in[15];
  const float* glu1b   = (const float*)d_in[16];
  const float* glu2w   = (const float*)d_in[17];
  float* out = (float*)d_out;

  // workspace layout (float units); total ~43.3 MB
  float* W    = (float*)d_ws;
  float* h    = W;                 // 819200
  float* hl   = W + 819200;        // 819200
  float* hg   = W + 1638400;       // 819200
  float* e0p  = W + 2457600;       // 819200
  float* e1p  = W + 3276800;       // 6553600
  float* sess = W + 9830400;       // 16384
  float* g2   = W + 9846784;       // 16384
  float* sel  = W + 9863168;       // 16384
  float* sel2 = W + 9879552;       // 16384
  float* norms= W + 9895936;       // 128 (pad to 9896064)
  float* n1w  = W + 9896064;       // 51200
  float* n2w  = W + 9947264;       // 409600
  int*   n1i  = (int*)(W + 10356864);  // 51200
  int*   n2i  = n1i + 51200;           // 409600
  int*   pr   = n2i + 409600;          // 128
  int*   pc   = pr + 128;              // 50

  // embeddings + session mean + local aggregation
  k_gather_h<<<B_*L_, D_, 0, stream>>>(inputs, emb, h);
  k_sess<<<B_, D_, 0, stream>>>(item, mask, emb, sess);
  k_local<<<B_, 256, 0, stream>>>(h, adj, a_local, hl);

  // neighbor sampling (2 hops)
  k_sample<<<(B_*L_*S_ + 255)/256, 256, 0, stream>>>(inputs, adj_all, num_w, B_*L_*S_, n1i, n1w);
  k_sample<<<(B_*L_*S_*S_ + 255)/256, 256, 0, stream>>>(n1i, adj_all, num_w, B_*L_*S_*S_, n2i, n2w);

  const int M0 = L_;        // 50
  const int M1 = L_*S_;     // 400
  // hop0 i=0: self = h, neigh = emb[n1i]  -> e0p
  k_gagg_att<<<dim3((M0+7)/8, B_), 256, 0, stream>>>(emb, nullptr, n1i, n1w, sess, gw1, gw2, e0p, M0, 8);
  k_gagg_out<<<256, 256, 0, stream>>>(emb, h, nullptr, gw3, e0p, B_*M0, (B_*M0+255)/256);
  // hop0 i=1: self = emb[n1i], neigh = emb[n2i] -> e1p
  k_gagg_att<<<dim3(M1/8, B_), 256, 0, stream>>>(emb, nullptr, n2i, n2w, sess, gw1, gw2, e1p, M1, 8);
  k_gagg_out<<<256, 256, 0, stream>>>(emb, nullptr, n1i, gw3, e1p, B_*M1, (B_*M1+255)/256);
  // hop1: self = e0p, neigh = e1p -> hg   (weights index 1)
  k_gagg_att<<<dim3((M0+7)/8, B_), 256, 0, stream>>>(emb, e1p, nullptr, n1w, sess,
                                                     gw1 + 129*D_, gw2 + D_, hg, M0, 8);
  k_gagg_out<<<256, 256, 0, stream>>>(emb, e0p, nullptr, gw3 + 256*D_, hg, B_*M0, (B_*M0+255)/256);

  // output = hl + hg (and zero the loss slot)
  k_addout<<<(B_*L_*D_ + 1 + 255)/256, 256, 0, stream>>>(hl, hg, out);

  // SSL loss
  k_perms<<<1, 128, 0, stream>>>(pr, pc);
  k_ssl<<<B_, 128, 0, stream>>>(hl, hg, pr, pc, out + B_*L_*D_);

  // scoring head
  k_hs<<<B_, D_, 0, stream>>>(out, mask, glu2w, g2);
  k_select<<<B_, D_, 0, stream>>>(out, mask, pose, w1, w2, glu1w, glu1b, g2, sel, norms);
  k_topk<<<B_, 128, 0, stream>>>(sel, norms, sel2);
  k_scores<<<dim3((NSC_ + 31)/32, 2), 256, 0, stream>>>(sel2, emb, out + B_*L_*D_ + 1);
}

// Round 2
// 590.836 us; speedup vs baseline: 2.8163x; 2.8163x over previous
//
#include <hip/hip_runtime.h>
#include <stdint.h>

// ---------------- constants ----------------
namespace {
constexpr int B_ = 128;
constexpr int L_ = 50;
constexpr int D_ = 128;
constexpr int S_ = 8;
constexpr int NSC_ = 99999;       // NUM_NODE-1
constexpr int NBR_ = 9;
}
#define LEAKY_ 0.2f
#define BETA_ 0.005f

typedef __attribute__((ext_vector_type(8))) __bf16 bf16x8;
typedef __attribute__((ext_vector_type(4))) float f32x4;

__device__ __forceinline__ float leaky_(float x){ return x >= 0.f ? x : LEAKY_*x; }
__device__ __forceinline__ float sigm_(float x){ return 1.f/(1.f+expf(-x)); }

// RNE float->bf16 bits (finite inputs)
__device__ __forceinline__ short f2b(float f){
  uint32_t u = __float_as_uint(f);
  u += 0x7fffu + ((u >> 16) & 1u);
  return (short)(u >> 16);
}
__device__ __forceinline__ float b2f(short s){
  return __uint_as_float(((uint32_t)(uint16_t)s) << 16);
}
__device__ __forceinline__ f32x4 zero4(){ f32x4 z = {0.f,0.f,0.f,0.f}; return z; }
__device__ __forceinline__ bf16x8 cvt8(float4 a, float4 b){
  union { short s[8]; bf16x8 v; } u;
  u.s[0]=f2b(a.x); u.s[1]=f2b(a.y); u.s[2]=f2b(a.z); u.s[3]=f2b(a.w);
  u.s[4]=f2b(b.x); u.s[5]=f2b(b.y); u.s[6]=f2b(b.z); u.s[7]=f2b(b.w);
  return u.v;
}
__device__ __forceinline__ f32x4 mfma_bf16(bf16x8 a, bf16x8 b, f32x4 c){
  return __builtin_amdgcn_mfma_f32_16x16x32_bf16(a, b, c, 0, 0, 0);
}

// ---------------- threefry2x32 (JAX-compatible) ----------------
__device__ __forceinline__ void tf2x32(uint32_t k0, uint32_t k1, uint32_t c0, uint32_t c1,
                                       uint32_t* o0, uint32_t* o1){
  uint32_t ks2 = k0 ^ k1 ^ 0x1BD11BDAu;
  uint32_t x0 = c0 + k0, x1 = c1 + k1;
#define RND_(r) { x0 += x1; x1 = (x1<<(r))|(x1>>(32-(r))); x1 ^= x0; }
  RND_(13) RND_(15) RND_(26) RND_(6)   x0 += k1;  x1 += ks2 + 1u;
  RND_(17) RND_(29) RND_(16) RND_(24)  x0 += ks2; x1 += k0  + 2u;
  RND_(13) RND_(15) RND_(26) RND_(6)   x0 += k0;  x1 += k1  + 3u;
  RND_(17) RND_(29) RND_(16) RND_(24)  x0 += k1;  x1 += ks2 + 4u;
  RND_(13) RND_(15) RND_(26) RND_(6)   x0 += ks2; x1 += k0  + 5u;
#undef RND_
  *o0 = x0; *o1 = x1;
}

// ---------------- prep: transposed / bf16 weight copies ----------------
__global__ void k_prep(const float* __restrict__ gw1, const float* __restrict__ gw3,
                       const float* __restrict__ glu1w,
                       float* __restrict__ w1T, float* __restrict__ glu1wT,
                       short* __restrict__ w3T){
  int o = blockIdx.x*256 + threadIdx.x;
  if (o < 32768){                       // w1T[hop][d][e] = gw1[hop][e][d]
    int hop = o >> 14, r = o & 16383;
    int d = r >> 7, e = r & 127;
    w1T[o] = gw1[hop*(129*128) + e*128 + d];
  } else if (o < 49152){                // glu1wT[e][t] = glu1w[t][e]
    int o2 = o - 32768;
    int e = o2 >> 7, t = o2 & 127;
    glu1wT[o2] = glu1w[t*128 + e];
  } else if (o < 114688){               // w3T[hop][n][k] = bf16(gw3[hop][k][n]), stride 264
    int o3 = o - 49152;
    int hop = o3 >> 15, r = o3 & 32767;
    int nn = r >> 8, k = r & 255;
    w3T[hop*(128*264) + nn*264 + k] = f2b(gw3[hop*(256*128) + k*128 + nn]);
  }
}

// ---------------- sess = mean of masked item embeddings ----------------
__global__ void k_sess(const int* __restrict__ item, const int* __restrict__ mask,
                       const float* __restrict__ emb, float* __restrict__ sess){
  int b = blockIdx.x, t = threadIdx.x;
  float acc = 0.f, ms = 0.f;
  for (int l = 0; l < L_; l++){
    float mk = (float)mask[b*L_ + l];
    ms += mk;
    acc += mk * emb[(size_t)item[b*L_ + l]*D_ + t];
  }
  sess[(size_t)b*D_ + t] = acc / ms;
}

// ---------------- local GAT aggregation ----------------
__global__ __launch_bounds__(256) void k_local(const int* __restrict__ inputs,
                                               const float* __restrict__ emb,
                                               const int* __restrict__ adj,
                                               const float* __restrict__ a_local,
                                               float* __restrict__ hl){
  __shared__ float hs[L_*129];
  __shared__ float att[L_*52];
  __shared__ float al[4*132];
  __shared__ int idxs[L_];
  int b = blockIdx.x, tid = threadIdx.x;
  if (tid < L_) idxs[tid] = inputs[b*L_ + tid];
  __syncthreads();
  for (int e = tid; e < L_*D_; e += 256){
    int i = e >> 7, d = e & 127;
    hs[i*129 + d] = emb[(size_t)idxs[i]*D_ + d];
  }
  for (int e = tid; e < 4*D_; e += 256) al[(e>>7)*132 + (e&127)] = a_local[e];
  __syncthreads();
  for (int p = tid; p < L_*L_; p += 256){
    int i = p / L_, j = p % L_;
    int k = adj[((size_t)b*L_ + i)*L_ + j];
    float v = -9e15f;
    if (k >= 1){
      const float* ak = &al[(k-1)*132];
      float acc = 0.f;
      for (int d = 0; d < D_; d++) acc += hs[i*129+d]*hs[j*129+d]*ak[d];
      v = leaky_(acc);
    }
    att[i*52 + j] = v;
  }
  __syncthreads();
  if (tid < L_){
    int i = tid;
    float mx = -INFINITY;
    for (int j = 0; j < L_; j++) mx = fmaxf(mx, att[i*52+j]);
    float sm = 0.f;
    for (int j = 0; j < L_; j++){ float e_ = expf(att[i*52+j] - mx); att[i*52+j] = e_; sm += e_; }
    float inv = 1.f/sm;
    for (int j = 0; j < L_; j++) att[i*52+j] *= inv;
  }
  __syncthreads();
  for (int q = tid; q < L_*D_; q += 256){
    int i = q >> 7, d = q & 127;
    float acc = 0.f;
    for (int j = 0; j < L_; j++) acc += att[i*52+j]*hs[j*129+d];
    hl[((size_t)b*L_ + i)*D_ + d] = acc;
  }
}

// ---------------- neighbor sampling ----------------
__global__ void k_sample(const int* __restrict__ src, const int* __restrict__ adj_all,
                         const float* __restrict__ num_w, int n,
                         int* __restrict__ out_i, float* __restrict__ out_w){
  int p = blockIdx.x*blockDim.x + threadIdx.x;
  if (p < n){
    int base = src[p >> 3];
    int off  = base*S_ + (p & 7);
    out_i[p] = adj_all[off];
    out_w[p] = num_w[off];
  }
}

// ---------------- MFMA global-agg attention ----------------
// logits = leaky((nv .* sess)@w1 + nw*w1[128]) @ w2; softmax per 8; neigh = sum alpha*nv
__global__ __launch_bounds__(256) void k_att(
    const float* __restrict__ emb, const float* __restrict__ dense,
    const int* __restrict__ nidx, const float* __restrict__ nw,
    const float* __restrict__ sess, const float* __restrict__ w1T,
    const float* __restrict__ w1g, const float* __restrict__ w2g,
    float* __restrict__ outn, int rpb)
{
  __shared__ __align__(16) short As[128*136];
  __shared__ __align__(16) short Bs[128*136];
  __shared__ float sessS[128], w1lS[128], w2S[128], nwsS[128];
  __shared__ float logitsS[128], alphaS[128];
  const int tid = threadIdx.x;
  const int b = blockIdx.y;
  const int r0 = blockIdx.x * 128;
  if (tid < 128){
    sessS[tid] = sess[(size_t)b*128 + tid];
    w1lS[tid]  = w1g[128*128 + tid];
    w2S[tid]   = w2g[tid];
    int rr = min(r0 + tid, rpb - 1);
    nwsS[tid]  = nw[(size_t)b*rpb + rr];
  }
  __syncthreads();
  // stage A rows (bf16)
  for (int it = 0; it < 16; it++){
    int u = it*256 + tid;
    int lr = u >> 5, c = u & 31;
    int rr = min(r0 + lr, rpb - 1);
    size_t gr = (size_t)b*rpb + rr;
    const float* src = dense ? dense + gr*128 : emb + (size_t)nidx[gr]*128;
    float4 v = *(const float4*)(src + c*4);
    short4 s; s.x=f2b(v.x); s.y=f2b(v.y); s.z=f2b(v.z); s.w=f2b(v.w);
    *(short4*)&As[lr*136 + c*4] = s;
  }
  // stage B^T: Bs[d][e] = bf16(w1[e][d]*sess[e])
  for (int it = 0; it < 64; it++){
    int u = it*256 + tid;
    int d = u >> 7, e = u & 127;
    Bs[d*136 + e] = f2b(w1T[d*128 + e] * sessS[e]);
  }
  __syncthreads();
  const int lane = tid & 63, wave = tid >> 6;
  const int quad = lane >> 4, l16 = lane & 15;
  const int wr0 = wave * 32;
  f32x4 acc[2][8];
#pragma unroll
  for (int i=0;i<2;i++)
#pragma unroll
    for (int j=0;j<8;j++) acc[i][j] = zero4();
  for (int kc = 0; kc < 4; kc++){
    int k = kc*32 + quad*8;
    bf16x8 a0 = *(const bf16x8*)&As[(wr0 + l16)*136 + k];
    bf16x8 a1 = *(const bf16x8*)&As[(wr0 + 16 + l16)*136 + k];
#pragma unroll
    for (int nt = 0; nt < 8; nt++){
      bf16x8 bb = *(const bf16x8*)&Bs[(nt*16 + l16)*136 + k];
      acc[0][nt] = mfma_bf16(a0, bb, acc[0][nt]);
      acc[1][nt] = mfma_bf16(a1, bb, acc[1][nt]);
    }
  }
#pragma unroll
  for (int rt = 0; rt < 2; rt++){
#pragma unroll
    for (int r = 0; r < 4; r++){
      int rowl = wr0 + rt*16 + quad*4 + r;
      float nwv = nwsS[rowl];
      float c = 0.f;
#pragma unroll
      for (int nt = 0; nt < 8; nt++){
        int col = nt*16 + l16;
        float v = acc[rt][nt][r] + nwv * w1lS[col];
        c += leaky_(v) * w2S[col];
      }
      c += __shfl_xor(c, 1, 64);
      c += __shfl_xor(c, 2, 64);
      c += __shfl_xor(c, 4, 64);
      c += __shfl_xor(c, 8, 64);
      if (l16 == 0) logitsS[rowl] = c;
    }
  }
  __syncthreads();
  if (tid < 16){
    float mx = -INFINITY;
    for (int s = 0; s < 8; s++) mx = fmaxf(mx, logitsS[tid*8+s]);
    float sm = 0.f; float ev[8];
    for (int s = 0; s < 8; s++){ ev[s] = expf(logitsS[tid*8+s]-mx); sm += ev[s]; }
    for (int s = 0; s < 8; s++) alphaS[tid*8+s] = ev[s]/sm;
  }
  __syncthreads();
  for (int it = 0; it < 8; it++){
    int o = it*256 + tid;
    int mg = o >> 7, d = o & 127;
    if (r0 + mg*8 < rpb){
      float a = 0.f;
#pragma unroll
      for (int s = 0; s < 8; s++)
        a += alphaS[mg*8+s] * b2f(As[(mg*8+s)*136 + d]);
      int m = (r0 >> 3) + mg;
      outn[((size_t)b*(rpb>>3) + m)*128 + d] = a;
    }
  }
}

// ---------------- MFMA global-agg output: inout = relu([self||neigh]@w3) ----------------
__global__ __launch_bounds__(256) void k_gout(
    const float* __restrict__ emb, const float* __restrict__ self_dense,
    const int* __restrict__ self_idx, const short* __restrict__ w3T,
    float* __restrict__ inout)
{
  const int tid = threadIdx.x;
  const int lane = tid & 63, wave = tid >> 6;
  const int quad = lane >> 4, l16 = lane & 15;
  const int rbase = blockIdx.x*64 + wave*16;
  const int row = rbase + l16;
  const float* selfp = self_dense ? self_dense + (size_t)row*128
                                  : emb + (size_t)self_idx[row]*128;
  const float* neighp = inout + (size_t)row*128;
  f32x4 acc[8];
#pragma unroll
  for (int i=0;i<8;i++) acc[i] = zero4();
  for (int kc = 0; kc < 8; kc++){
    int k = kc*32 + quad*8;
    const float* ap = (k < 128) ? (selfp + k) : (neighp + (k-128));
    float4 f0 = *(const float4*)ap;
    float4 f1 = *(const float4*)(ap+4);
    bf16x8 a = cvt8(f0, f1);
#pragma unroll
    for (int nt = 0; nt < 8; nt++){
      bf16x8 bb = *(const bf16x8*)&w3T[(size_t)(nt*16 + l16)*264 + k];
      acc[nt] = mfma_bf16(a, bb, acc[nt]);
    }
  }
#pragma unroll
  for (int nt = 0; nt < 8; nt++)
#pragma unroll
    for (int r = 0; r < 4; r++){
      int orow = rbase + quad*4 + r;
      inout[(size_t)orow*128 + nt*16 + l16] = fmaxf(acc[nt][r], 0.f);
    }
}

// ---------------- output = hl + hg; zero loss slot ----------------
__global__ void k_addout(const float* __restrict__ hl, const float* __restrict__ hg,
                         float* __restrict__ out){
  int i = blockIdx.x*256 + threadIdx.x;
  if (i < B_*L_*D_) out[i] = hl[i] + hg[i];
  else if (i == B_*L_*D_) out[i] = 0.f;
}

// ---------------- jax.random permutations ----------------
__global__ void k_perms(int* __restrict__ pr, int* __restrict__ pc){
  __shared__ uint32_t keys[128];
  int tid = threadIdx.x;
  uint32_t kr0, kr1, kc0, kc1, sk0, sk1, o0, o1;
  tf2x32(0u, 42u, 0u, 0u, &kr0, &kr1);
  tf2x32(0u, 42u, 0u, 1u, &kc0, &kc1);
  tf2x32(kr0, kr1, 0u, 1u, &sk0, &sk1);
  tf2x32(sk0, sk1, 0u, (uint32_t)tid, &o0, &o1);
  keys[tid] = o0 ^ o1;
  __syncthreads();
  {
    uint32_t mk = keys[tid];
    int rank = 0;
    for (int j = 0; j < 128; j++){
      uint32_t kj = keys[j];
      rank += (kj < mk) || (kj == mk && j < tid);
    }
    pr[rank] = tid;
  }
  __syncthreads();
  tf2x32(kc0, kc1, 0u, 1u, &sk0, &sk1);
  if (tid < 50){
    tf2x32(sk0, sk1, 0u, (uint32_t)tid, &o0, &o1);
    keys[tid] = o0 ^ o1;
  }
  __syncthreads();
  if (tid < 50){
    uint32_t mk = keys[tid];
    int rank = 0;
    for (int j = 0; j < 50; j++){
      uint32_t kj = keys[j];
      rank += (kj < mk) || (kj == mk && j < tid);
    }
    pc[rank] = tid;
  }
}

// ---------------- SSL loss ----------------
__global__ void k_ssl(const float* __restrict__ hl, const float* __restrict__ hg,
                      const int* __restrict__ pr, const int* __restrict__ pc,
                      float* __restrict__ out_loss){
  __shared__ float red[128];
  int b = blockIdx.x, d = threadIdx.x;
  int prb = pr[b];
  float pos = 0.f, neg = 0.f;
  for (int l = 0; l < L_; l++){
    float hgv = hg[((size_t)b*L_ + l)*D_ + d];
    pos += hl[((size_t)b*L_ + l)*D_ + d] * hgv;
    neg += hgv * hl[((size_t)prb*L_ + pc[l])*D_ + d];
  }
  float term = -logf(1e-8f + sigm_(pos)) - logf(1e-8f + 1.f - sigm_(neg));
  red[d] = term;
  __syncthreads();
  for (int off = 64; off >= 1; off >>= 1){
    if (d < off) red[d] += red[d + off];
    __syncthreads();
  }
  if (d == 0) atomicAdd(out_loss, BETA_*red[0]);
}

// ---------------- hs then g2 = hs @ glu2_w.T ----------------
__global__ void k_hs(const float* __restrict__ hidden, const int* __restrict__ mask,
                     const float* __restrict__ glu2_w, float* __restrict__ g2){
  __shared__ float hss[D_];
  int b = blockIdx.x, t = threadIdx.x;
  float acc = 0.f, ms = 0.f;
  for (int l = 0; l < L_; l++){
    float mk = (float)mask[b*L_ + l];
    ms += mk;
    acc += mk * hidden[((size_t)b*L_ + l)*D_ + t];
  }
  hss[t] = acc / ms;
  __syncthreads();
  float g = 0.f;
  for (int e = 0; e < D_; e++) g += hss[e]*glu2_w[t*D_ + e];
  g2[(size_t)b*D_ + t] = g;
}

// ---------------- beta[b,l] (parallel over (b,l)) ----------------
__global__ __launch_bounds__(128) void k_beta(
    const float* __restrict__ hidden, const int* __restrict__ mask,
    const float* __restrict__ pose, const float* __restrict__ w1s,
    const float* __restrict__ w2s, const float* __restrict__ glu1wT,
    const float* __restrict__ glu1b, const float* __restrict__ g2,
    float* __restrict__ betaW)
{
  __shared__ float hrow[128], prow[128], nh[128], red[128];
  int l = blockIdx.x, b = blockIdx.y, t = threadIdx.x;
  hrow[t] = hidden[((size_t)b*L_ + l)*128 + t];
  prow[t] = pose[l*128 + t];
  __syncthreads();
  float acc = 0.f;
  for (int e = 0; e < 128; e++) acc += prow[e]*w1s[e*128 + t];
  for (int e = 0; e < 128; e++) acc += hrow[e]*w1s[(128+e)*128 + t];
  nh[t] = tanhf(acc);
  __syncthreads();
  float a2 = 0.f;
  for (int e = 0; e < 128; e++) a2 += nh[e]*glu1wT[e*128 + t];
  float ns = sigm_(a2 + glu1b[t] + g2[(size_t)b*128 + t]);
  red[t] = ns * w2s[t];
  __syncthreads();
  for (int off = 64; off >= 1; off >>= 1){
    if (t < off) red[t] += red[t+off];
    __syncthreads();
  }
  if (t == 0) betaW[b*L_ + l] = red[0] * (float)mask[b*L_ + l];
}

// ---------------- select = sum_l beta*hidden; norms ----------------
__global__ __launch_bounds__(128) void k_selnorm(
    const float* __restrict__ hidden, const float* __restrict__ betaW,
    float* __restrict__ select, float* __restrict__ norms)
{
  __shared__ float bet[56];
  __shared__ float red[128];
  int b = blockIdx.x, t = threadIdx.x;
  if (t < L_) bet[t] = betaW[b*L_ + t];
  __syncthreads();
  float sel = 0.f;
  for (int l = 0; l < L_; l++) sel += bet[l]*hidden[((size_t)b*L_ + l)*128 + t];
  select[(size_t)b*128 + t] = sel;
  red[t] = sel*sel + 1e-6f;
  __syncthreads();
  for (int off=64; off>=1; off>>=1){ if (t<off) red[t]+=red[t+off]; __syncthreads(); }
  if (t==0) norms[b] = sqrtf(red[0]);
}

// ---------------- cosine softmax + top-9 + neighbor mix ----------------
__global__ __launch_bounds__(128) void k_topk(const float* __restrict__ select,
                                              const float* __restrict__ norms,
                                              float* __restrict__ select2){
  __shared__ float p[B_];
  __shared__ float red[128];
  __shared__ float tv[NBR_];
  __shared__ int   ti[NBR_];
  int b = blockIdx.x, t = threadIdx.x;
  float dot = 0.f;
  for (int d = 0; d < D_; d++) dot += select[(size_t)b*D_ + d]*select[(size_t)t*D_ + d];
  float logit = dot / (norms[b]*norms[t]);
  red[t] = logit; __syncthreads();
  for (int off = 64; off >= 1; off >>= 1){
    if (t < off) red[t] = fmaxf(red[t], red[t + off]);
    __syncthreads();
  }
  float mx = red[0]; __syncthreads();
  float e_ = expf(logit - mx);
  red[t] = e_; __syncthreads();
  for (int off = 64; off >= 1; off >>= 1){
    if (t < off) red[t] += red[t + off];
    __syncthreads();
  }
  p[t] = e_ / red[0];
  __syncthreads();
  if (t == 0){
    unsigned long long used0 = 0ull, used1 = 0ull;
    for (int k = 0; k < NBR_; k++){
      float best = -INFINITY; int bi = 0;
      for (int j = 0; j < B_; j++){
        bool u = (j < 64) ? ((used0 >> j) & 1ull) : ((used1 >> (j-64)) & 1ull);
        if (!u && p[j] > best){ best = p[j]; bi = j; }
      }
      if (bi < 64) used0 |= 1ull << bi; else used1 |= 1ull << (bi-64);
      tv[k] = best; ti[k] = bi;
    }
    float mx2 = -INFINITY;
    for (int k = 0; k < NBR_; k++) mx2 = fmaxf(mx2, tv[k]);
    float s2 = 0.f;
    for (int k = 0; k < NBR_; k++){ tv[k] = expf(tv[k]-mx2); s2 += tv[k]; }
    for (int k = 0; k < NBR_; k++) tv[k] /= s2;
  }
  __syncthreads();
  float nb = 0.f;
#pragma unroll
  for (int k = 0; k < NBR_; k++) nb += tv[k]*select[(size_t)ti[k]*D_ + t];
  select2[(size_t)b*D_ + t] = select[(size_t)b*D_ + t] + nb;
}

// ---------------- MFMA scores = sel2 @ emb[1:].T ----------------
__global__ __launch_bounds__(256) void k_scores(
    const float* __restrict__ sel2, const float* __restrict__ emb,
    float* __restrict__ scores)
{
  __shared__ __align__(16) short Ss[128*136];
  const int tid = threadIdx.x;
  for (int it = 0; it < 16; it++){
    int u = it*256 + tid;
    int r = u >> 5, c = u & 31;
    float4 v = *(const float4*)(sel2 + r*128 + c*4);
    short4 s; s.x=f2b(v.x); s.y=f2b(v.y); s.z=f2b(v.z); s.w=f2b(v.w);
    *(short4*)&Ss[r*136 + c*4] = s;
  }
  __syncthreads();
  const int lane = tid & 63, wave = tid >> 6;
  const int quad = lane >> 4, l16 = lane & 15;
  int n = blockIdx.x*64 + wave*16 + l16;
  bool nvalid = (n < NSC_);
  const float* embrow = emb + (size_t)(1 + (nvalid ? n : 0))*128;
  f32x4 acc[8];
#pragma unroll
  for (int i=0;i<8;i++) acc[i] = zero4();
  for (int kc = 0; kc < 4; kc++){
    int k = kc*32 + quad*8;
    float4 f0 = *(const float4*)(embrow + k);
    float4 f1 = *(const float4*)(embrow + k + 4);
    bf16x8 bb = cvt8(f0, f1);
#pragma unroll
    for (int rt = 0; rt < 8; rt++){
      bf16x8 a = *(const bf16x8*)&Ss[(rt*16 + l16)*136 + k];
      acc[rt] = mfma_bf16(a, bb, acc[rt]);
    }
  }
  if (nvalid){
#pragma unroll
    for (int rt = 0; rt < 8; rt++)
#pragma unroll
      for (int r = 0; r < 4; r++){
        int brow = rt*16 + quad*4 + r;
        scores[(size_t)brow*NSC_ + n] = acc[rt][r];
      }
  }
}

// ---------------- launcher ----------------
extern "C" void kernel_launch(void* const* d_in, const int* in_sizes, int n_in,
                              void* d_out, int out_size, void* d_ws, size_t ws_size,
                              hipStream_t stream) {
  (void)in_sizes; (void)n_in; (void)out_size; (void)ws_size;
  const int*   inputs  = (const int*)  d_in[0];
  const int*   adj     = (const int*)  d_in[1];
  const int*   mask    = (const int*)  d_in[2];
  const int*   item    = (const int*)  d_in[3];
  const int*   adj_all = (const int*)  d_in[5];
  const float* num_w   = (const float*)d_in[6];
  const float* emb     = (const float*)d_in[7];
  const float* pose    = (const float*)d_in[8];
  const float* a_local = (const float*)d_in[9];
  const float* gw1     = (const float*)d_in[10];
  const float* gw2     = (const float*)d_in[11];
  const float* gw3     = (const float*)d_in[12];
  const float* w1      = (const float*)d_in[13];
  const float* w2      = (const float*)d_in[14];
  const float* glu1w   = (const float*)d_in[15];
  const float* glu1b   = (const float*)d_in[16];
  const float* glu2w   = (const float*)d_in[17];
  float* out = (float*)d_out;

  // workspace layout (float units), total ~40.4 MB
  float* W     = (float*)d_ws;
  float* hl    = W;                    // 819200
  float* hg    = W + 819200;           // 819200
  float* e0p   = W + 1638400;          // 819200
  float* e1p   = W + 2457600;          // 6553600
  float* sess  = W + 9011200;          // 16384
  float* g2    = W + 9027584;          // 16384
  float* sel   = W + 9043968;          // 16384
  float* sel2  = W + 9060352;          // 16384
  float* norms = W + 9076736;          // 256
  float* n1w   = W + 9076992;          // 51200
  float* n2w   = W + 9128192;          // 409600
  float* betaW = W + 9537792;          // 6400
  float* w1T   = W + 9544192;          // 32768 (2 hops)
  float* glu1wT= W + 9576960;          // 16384
  short* w3Tb  = (short*)(W + 9593344);// 2*128*264 shorts = 33792 floats
  int*   n1i   = (int*)(W + 9627136);  // 51200
  int*   n2i   = n1i + 51200;          // 409600
  int*   pr    = n2i + 409600;         // 128
  int*   pc    = pr + 128;             // 50

  k_prep<<<448, 256, 0, stream>>>(gw1, gw3, glu1w, w1T, glu1wT, w3Tb);
  k_sess<<<B_, D_, 0, stream>>>(item, mask, emb, sess);
  k_local<<<B_, 256, 0, stream>>>(inputs, emb, adj, a_local, hl);

  k_sample<<<(B_*L_*S_ + 255)/256, 256, 0, stream>>>(inputs, adj_all, num_w, B_*L_*S_, n1i, n1w);
  k_sample<<<(B_*L_*S_*S_ + 255)/256, 256, 0, stream>>>(n1i, adj_all, num_w, B_*L_*S_*S_, n2i, n2w);

  // hop0 i=0: self=emb[inputs], neigh=emb[n1i] -> e0p   (rpb=400)
  k_att <<<dim3(4, B_),  256, 0, stream>>>(emb, nullptr, n1i, n1w, sess, w1T, gw1, gw2, e0p, 400);
  k_gout<<<100, 256, 0, stream>>>(emb, nullptr, inputs, w3Tb, e0p);
  // hop0 i=1: self=emb[n1i], neigh=emb[n2i] -> e1p      (rpb=3200)
  k_att <<<dim3(25, B_), 256, 0, stream>>>(emb, nullptr, n2i, n2w, sess, w1T, gw1, gw2, e1p, 3200);
  k_gout<<<800, 256, 0, stream>>>(emb, nullptr, n1i, w3Tb, e1p);
  // hop1: self=e0p, neigh=e1p -> hg                     (rpb=400, weights[1])
  k_att <<<dim3(4, B_),  256, 0, stream>>>(emb, e1p, nullptr, n1w, sess, w1T + 16384,
                                           gw1 + 129*128, gw2 + 128, hg, 400);
  k_gout<<<100, 256, 0, stream>>>(emb, e0p, nullptr, w3Tb + 128*264, hg);

  k_addout<<<(B_*L_*D_ + 1 + 255)/256, 256, 0, stream>>>(hl, hg, out);

  k_perms<<<1, 128, 0, stream>>>(pr, pc);
  k_ssl<<<B_, 128, 0, stream>>>(hl, hg, pr, pc, out + B_*L_*D_);

  k_hs<<<B_, D_, 0, stream>>>(out, mask, glu2w, g2);
  k_beta<<<dim3(L_, B_), 128, 0, stream>>>(out, mask, pose, w1, w2, glu1wT, glu1b, g2, betaW);
  k_selnorm<<<B_, 128, 0, stream>>>(out, betaW, sel, norms);
  k_topk<<<B_, 128, 0, stream>>>(sel, norms, sel2);
  k_scores<<<(NSC_ + 63)/64, 256, 0, stream>>>(sel2, emb, out + B_*L_*D_ + 1);
}

// Round 3
// 586.324 us; speedup vs baseline: 2.8380x; 1.0077x over previous
//
#include <hip/hip_runtime.h>
#include <stdint.h>

// ---------------- constants ----------------
namespace {
constexpr int B_ = 128;
constexpr int L_ = 50;
constexpr int D_ = 128;
constexpr int S_ = 8;
constexpr int NSC_ = 99999;       // NUM_NODE-1
constexpr int NBR_ = 9;
}
#define LEAKY_ 0.2f
#define BETA_ 0.005f

typedef __attribute__((ext_vector_type(8))) __bf16 bf16x8;
typedef __attribute__((ext_vector_type(4))) float f32x4;

__device__ __forceinline__ float leaky_(float x){ return x >= 0.f ? x : LEAKY_*x; }
__device__ __forceinline__ float sigm_(float x){ return 1.f/(1.f+expf(-x)); }

// RNE float->bf16 bits (finite inputs)
__device__ __forceinline__ short f2b(float f){
  uint32_t u = __float_as_uint(f);
  u += 0x7fffu + ((u >> 16) & 1u);
  return (short)(u >> 16);
}
__device__ __forceinline__ float b2f(short s){
  return __uint_as_float(((uint32_t)(uint16_t)s) << 16);
}
__device__ __forceinline__ f32x4 zero4(){ f32x4 z = {0.f,0.f,0.f,0.f}; return z; }
__device__ __forceinline__ bf16x8 cvt8(float4 a, float4 b){
  union { short s[8]; bf16x8 v; } u;
  u.s[0]=f2b(a.x); u.s[1]=f2b(a.y); u.s[2]=f2b(a.z); u.s[3]=f2b(a.w);
  u.s[4]=f2b(b.x); u.s[5]=f2b(b.y); u.s[6]=f2b(b.z); u.s[7]=f2b(b.w);
  return u.v;
}
__device__ __forceinline__ f32x4 mfma_bf16(bf16x8 a, bf16x8 b, f32x4 c){
  return __builtin_amdgcn_mfma_f32_16x16x32_bf16(a, b, c, 0, 0, 0);
}

// ---------------- threefry2x32 (JAX-compatible) ----------------
__device__ __forceinline__ void tf2x32(uint32_t k0, uint32_t k1, uint32_t c0, uint32_t c1,
                                       uint32_t* o0, uint32_t* o1){
  uint32_t ks2 = k0 ^ k1 ^ 0x1BD11BDAu;
  uint32_t x0 = c0 + k0, x1 = c1 + k1;
#define RND_(r) { x0 += x1; x1 = (x1<<(r))|(x1>>(32-(r))); x1 ^= x0; }
  RND_(13) RND_(15) RND_(26) RND_(6)   x0 += k1;  x1 += ks2 + 1u;
  RND_(17) RND_(29) RND_(16) RND_(24)  x0 += ks2; x1 += k0  + 2u;
  RND_(13) RND_(15) RND_(26) RND_(6)   x0 += k0;  x1 += k1  + 3u;
  RND_(17) RND_(29) RND_(16) RND_(24)  x0 += k1;  x1 += ks2 + 4u;
  RND_(13) RND_(15) RND_(26) RND_(6)   x0 += ks2; x1 += k0  + 5u;
#undef RND_
  *o0 = x0; *o1 = x1;
}

// ---------------- prep: transposed / bf16 weight copies ----------------
__global__ void k_prep(const float* __restrict__ gw1, const float* __restrict__ gw3,
                       const float* __restrict__ glu1w,
                       float* __restrict__ w1T, float* __restrict__ glu1wT,
                       short* __restrict__ w3T){
  int o = blockIdx.x*256 + threadIdx.x;
  if (o < 32768){                       // w1T[hop][d][e] = gw1[hop][e][d]
    int hop = o >> 14, r = o & 16383;
    int d = r >> 7, e = r & 127;
    w1T[o] = gw1[hop*(129*128) + e*128 + d];
  } else if (o < 49152){                // glu1wT[e][t] = glu1w[t][e]
    int o2 = o - 32768;
    int e = o2 >> 7, t = o2 & 127;
    glu1wT[o2] = glu1w[t*128 + e];
  } else if (o < 114688){               // w3T[hop][n][k] = bf16(gw3[hop][k][n]), stride 264
    int o3 = o - 49152;
    int hop = o3 >> 15, r = o3 & 32767;
    int nn = r >> 8, k = r & 255;
    w3T[hop*(128*264) + nn*264 + k] = f2b(gw3[hop*(256*128) + k*128 + nn]);
  }
}

// ---------------- sess = mean of masked item embeddings ----------------
__global__ void k_sess(const int* __restrict__ item, const int* __restrict__ mask,
                       const float* __restrict__ emb, float* __restrict__ sess){
  int b = blockIdx.x, t = threadIdx.x;
  float acc = 0.f, ms = 0.f;
  for (int l = 0; l < L_; l++){
    float mk = (float)mask[b*L_ + l];
    ms += mk;
    acc += mk * emb[(size_t)item[b*L_ + l]*D_ + t];
  }
  sess[(size_t)b*D_ + t] = acc / ms;
}

// ---------------- Bsess[hop][b][d][e] = bf16(w1T[hop][d][e]*sess[b][e]) ----------------
__global__ void k_bsess(const float* __restrict__ w1T, const float* __restrict__ sess,
                        short* __restrict__ Bsess){
  int blk = blockIdx.x;                // 256: hop = blk>>7, b = blk&127
  int hop = blk >> 7, b = blk & 127;
  int tid = threadIdx.x;
  const float* wt = w1T + hop*16384;
  short* outp = Bsess + ((size_t)hop*128 + b)*16384;
  __shared__ float sessS[128];
  if (tid < 128) sessS[tid] = sess[b*128 + tid];
  __syncthreads();
  for (int it = 0; it < 64; it++){
    int u = it*256 + tid;
    outp[u] = f2b(wt[u] * sessS[u & 127]);
  }
}

// ---------------- local GAT aggregation (split i-range over 2 blocks/b) ----------------
__global__ __launch_bounds__(256) void k_local(const int* __restrict__ inputs,
                                               const float* __restrict__ emb,
                                               const int* __restrict__ adj,
                                               const float* __restrict__ a_local,
                                               float* __restrict__ hl){
  __shared__ float hs[L_*129];
  __shared__ float att[25*52];
  __shared__ float al[4*132];
  __shared__ int idxs[L_];
  int b = blockIdx.y, half = blockIdx.x, tid = threadIdx.x;
  int i0 = half*25;
  if (tid < L_) idxs[tid] = inputs[b*L_ + tid];
  __syncthreads();
  for (int e = tid; e < L_*D_; e += 256){
    int i = e >> 7, d = e & 127;
    hs[i*129 + d] = emb[(size_t)idxs[i]*D_ + d];
  }
  for (int e = tid; e < 4*D_; e += 256) al[(e>>7)*132 + (e&127)] = a_local[e];
  __syncthreads();
  for (int p = tid; p < 25*L_; p += 256){
    int il = p / L_, j = p % L_;
    int i = i0 + il;
    int k = adj[((size_t)b*L_ + i)*L_ + j];
    float v = -9e15f;
    if (k >= 1){
      const float* ak = &al[(k-1)*132];
      float acc = 0.f;
      for (int d = 0; d < D_; d++) acc += hs[i*129+d]*hs[j*129+d]*ak[d];
      v = leaky_(acc);
    }
    att[il*52 + j] = v;
  }
  __syncthreads();
  if (tid < 25){
    int il = tid;
    float mx = -INFINITY;
    for (int j = 0; j < L_; j++) mx = fmaxf(mx, att[il*52+j]);
    float sm = 0.f;
    for (int j = 0; j < L_; j++){ float e_ = expf(att[il*52+j] - mx); att[il*52+j] = e_; sm += e_; }
    float inv = 1.f/sm;
    for (int j = 0; j < L_; j++) att[il*52+j] *= inv;
  }
  __syncthreads();
  for (int q = tid; q < 25*D_; q += 256){
    int il = q >> 7, d = q & 127;
    float acc = 0.f;
    for (int j = 0; j < L_; j++) acc += att[il*52+j]*hs[j*129+d];
    hl[((size_t)b*L_ + i0 + il)*D_ + d] = acc;
  }
}

// ---------------- neighbor sampling ----------------
__global__ void k_sample(const int* __restrict__ src, const int* __restrict__ adj_all,
                         const float* __restrict__ num_w, int n,
                         int* __restrict__ out_i, float* __restrict__ out_w){
  int p = blockIdx.x*blockDim.x + threadIdx.x;
  if (p < n){
    int base = src[p >> 3];
    int off  = base*S_ + (p & 7);
    out_i[p] = adj_all[off];
    out_w[p] = num_w[off];
  }
}

// ---------------- MFMA global-agg attention ----------------
// logits = leaky((nv .* sess)@w1 + nw*w1[128]) @ w2; softmax per 8; neigh = sum alpha*nv
__global__ __launch_bounds__(256, 4) void k_att(
    const float* __restrict__ emb, const float* __restrict__ dense,
    const int* __restrict__ nidx, const float* __restrict__ nw,
    const short* __restrict__ Bsess,   // [b][d=128][e=128] bf16 (hop slice)
    const float* __restrict__ w1g, const float* __restrict__ w2g,
    float* __restrict__ outn, int rpb)
{
  __shared__ __align__(16) short As[128*136];
  __shared__ float w1lS[128], w2S[128], nwsS[128], logitsS[128], alphaS[128];
  const int tid = threadIdx.x;
  const int b = blockIdx.y;
  const int r0 = blockIdx.x * 128;
  if (tid < 128){
    w1lS[tid]  = w1g[128*128 + tid];
    w2S[tid]   = w2g[tid];
    int rr = min(r0 + tid, rpb - 1);
    nwsS[tid]  = nw[(size_t)b*rpb + rr];
  }
  // stage A rows (bf16)
  for (int it = 0; it < 16; it++){
    int u = it*256 + tid;
    int lr = u >> 5, c = u & 31;
    int rr = min(r0 + lr, rpb - 1);
    size_t gr = (size_t)b*rpb + rr;
    const float* src = dense ? dense + gr*128 : emb + (size_t)nidx[gr]*128;
    float4 v = *(const float4*)(src + c*4);
    short4 s4; s4.x=f2b(v.x); s4.y=f2b(v.y); s4.z=f2b(v.z); s4.w=f2b(v.w);
    *(short4*)&As[lr*136 + c*4] = s4;
  }
  __syncthreads();
  const int lane = tid & 63, wave = tid >> 6;
  const int quad = lane >> 4, l16 = lane & 15;
  const int wr0 = wave * 32;
  const short* Bb = Bsess + (size_t)b*16384;
  f32x4 acc[2][8];
#pragma unroll
  for (int i=0;i<2;i++)
#pragma unroll
    for (int j=0;j<8;j++) acc[i][j] = zero4();
  for (int kc = 0; kc < 4; kc++){
    int k = kc*32 + quad*8;
    bf16x8 a0 = *(const bf16x8*)&As[(wr0 + l16)*136 + k];
    bf16x8 a1 = *(const bf16x8*)&As[(wr0 + 16 + l16)*136 + k];
    bf16x8 bb[8];
#pragma unroll
    for (int nt = 0; nt < 8; nt++)
      bb[nt] = *(const bf16x8*)&Bb[(size_t)(nt*16 + l16)*128 + k];
#pragma unroll
    for (int nt = 0; nt < 8; nt++){
      acc[0][nt] = mfma_bf16(a0, bb[nt], acc[0][nt]);
      acc[1][nt] = mfma_bf16(a1, bb[nt], acc[1][nt]);
    }
  }
#pragma unroll
  for (int rt = 0; rt < 2; rt++){
#pragma unroll
    for (int r = 0; r < 4; r++){
      int rowl = wr0 + rt*16 + quad*4 + r;
      float nwv = nwsS[rowl];
      float c = 0.f;
#pragma unroll
      for (int nt = 0; nt < 8; nt++){
        int col = nt*16 + l16;
        float v = acc[rt][nt][r] + nwv * w1lS[col];
        c += leaky_(v) * w2S[col];
      }
      c += __shfl_xor(c, 1, 64);
      c += __shfl_xor(c, 2, 64);
      c += __shfl_xor(c, 4, 64);
      c += __shfl_xor(c, 8, 64);
      if (l16 == 0) logitsS[rowl] = c;
    }
  }
  __syncthreads();
  if (tid < 16){
    float mx = -INFINITY;
    for (int s = 0; s < 8; s++) mx = fmaxf(mx, logitsS[tid*8+s]);
    float sm = 0.f; float ev[8];
    for (int s = 0; s < 8; s++){ ev[s] = expf(logitsS[tid*8+s]-mx); sm += ev[s]; }
    for (int s = 0; s < 8; s++) alphaS[tid*8+s] = ev[s]/sm;
  }
  __syncthreads();
  // weighted-sum epilogue: thread = (mg, 8-wide d-chunk), vector LDS reads
  {
    int mg = tid >> 4;         // 0..15
    int dc = tid & 15;         // 8 d each
    float o[8];
#pragma unroll
    for (int j = 0; j < 8; j++) o[j] = 0.f;
#pragma unroll
    for (int s = 0; s < 8; s++){
      float al = alphaS[mg*8+s];
      union { bf16x8 v; short sh[8]; } u;
      u.v = *(const bf16x8*)&As[(mg*8+s)*136 + dc*8];
#pragma unroll
      for (int j = 0; j < 8; j++) o[j] += al * b2f(u.sh[j]);
    }
    if (r0 + mg*8 < rpb){
      int m = (r0 >> 3) + mg;
      float* dst = outn + ((size_t)b*(rpb>>3) + m)*128 + dc*8;
      *(float4*)dst       = make_float4(o[0],o[1],o[2],o[3]);
      *(float4*)(dst + 4) = make_float4(o[4],o[5],o[6],o[7]);
    }
  }
}

// ---------------- MFMA global-agg output: inout = relu([self||neigh]@w3) ----------------
__global__ __launch_bounds__(256) void k_gout(
    const float* __restrict__ emb, const float* __restrict__ self_dense,
    const int* __restrict__ self_idx, const short* __restrict__ w3T,
    float* __restrict__ inout)
{
  const int tid = threadIdx.x;
  const int lane = tid & 63, wave = tid >> 6;
  const int quad = lane >> 4, l16 = lane & 15;
  const int rbase = blockIdx.x*64 + wave*16;
  const int row = rbase + l16;
  const float* selfp = self_dense ? self_dense + (size_t)row*128
                                  : emb + (size_t)self_idx[row]*128;
  const float* neighp = inout + (size_t)row*128;
  f32x4 acc[8];
#pragma unroll
  for (int i=0;i<8;i++) acc[i] = zero4();
  for (int kc = 0; kc < 8; kc++){
    int k = kc*32 + quad*8;
    const float* ap = (k < 128) ? (selfp + k) : (neighp + (k-128));
    float4 f0 = *(const float4*)ap;
    float4 f1 = *(const float4*)(ap+4);
    bf16x8 a = cvt8(f0, f1);
#pragma unroll
    for (int nt = 0; nt < 8; nt++){
      bf16x8 bb = *(const bf16x8*)&w3T[(size_t)(nt*16 + l16)*264 + k];
      acc[nt] = mfma_bf16(a, bb, acc[nt]);
    }
  }
#pragma unroll
  for (int nt = 0; nt < 8; nt++)
#pragma unroll
    for (int r = 0; r < 4; r++){
      int orow = rbase + quad*4 + r;
      inout[(size_t)orow*128 + nt*16 + l16] = fmaxf(acc[nt][r], 0.f);
    }
}

// ---------------- output = hl + hg; zero loss slot ----------------
__global__ void k_addout(const float* __restrict__ hl, const float* __restrict__ hg,
                         float* __restrict__ out){
  int i = blockIdx.x*256 + threadIdx.x;
  if (i < B_*L_*D_) out[i] = hl[i] + hg[i];
  else if (i == B_*L_*D_) out[i] = 0.f;
}

// ---------------- jax.random permutations ----------------
__global__ void k_perms(int* __restrict__ pr, int* __restrict__ pc){
  __shared__ uint32_t keys[128];
  int tid = threadIdx.x;
  uint32_t kr0, kr1, kc0, kc1, sk0, sk1, o0, o1;
  tf2x32(0u, 42u, 0u, 0u, &kr0, &kr1);
  tf2x32(0u, 42u, 0u, 1u, &kc0, &kc1);
  tf2x32(kr0, kr1, 0u, 1u, &sk0, &sk1);
  tf2x32(sk0, sk1, 0u, (uint32_t)tid, &o0, &o1);
  keys[tid] = o0 ^ o1;
  __syncthreads();
  {
    uint32_t mk = keys[tid];
    int rank = 0;
    for (int j = 0; j < 128; j++){
      uint32_t kj = keys[j];
      rank += (kj < mk) || (kj == mk && j < tid);
    }
    pr[rank] = tid;
  }
  __syncthreads();
  tf2x32(kc0, kc1, 0u, 1u, &sk0, &sk1);
  if (tid < 50){
    tf2x32(sk0, sk1, 0u, (uint32_t)tid, &o0, &o1);
    keys[tid] = o0 ^ o1;
  }
  __syncthreads();
  if (tid < 50){
    uint32_t mk = keys[tid];
    int rank = 0;
    for (int j = 0; j < 50; j++){
      uint32_t kj = keys[j];
      rank += (kj < mk) || (kj == mk && j < tid);
    }
    pc[rank] = tid;
  }
}

// ---------------- SSL loss ----------------
__global__ void k_ssl(const float* __restrict__ hl, const float* __restrict__ hg,
                      const int* __restrict__ pr, const int* __restrict__ pc,
                      float* __restrict__ out_loss){
  __shared__ float red[128];
  int b = blockIdx.x, d = threadIdx.x;
  int prb = pr[b];
  float pos = 0.f, neg = 0.f;
  for (int l = 0; l < L_; l++){
    float hgv = hg[((size_t)b*L_ + l)*D_ + d];
    pos += hl[((size_t)b*L_ + l)*D_ + d] * hgv;
    neg += hgv * hl[((size_t)prb*L_ + pc[l])*D_ + d];
  }
  float term = -logf(1e-8f + sigm_(pos)) - logf(1e-8f + 1.f - sigm_(neg));
  red[d] = term;
  __syncthreads();
  for (int off = 64; off >= 1; off >>= 1){
    if (d < off) red[d] += red[d + off];
    __syncthreads();
  }
  if (d == 0) atomicAdd(out_loss, BETA_*red[0]);
}

// ---------------- hs then g2 = hs @ glu2_w.T ----------------
__global__ void k_hs(const float* __restrict__ hidden, const int* __restrict__ mask,
                     const float* __restrict__ glu2_w, float* __restrict__ g2){
  __shared__ float hss[D_];
  int b = blockIdx.x, t = threadIdx.x;
  float acc = 0.f, ms = 0.f;
  for (int l = 0; l < L_; l++){
    float mk = (float)mask[b*L_ + l];
    ms += mk;
    acc += mk * hidden[((size_t)b*L_ + l)*D_ + t];
  }
  hss[t] = acc / ms;
  __syncthreads();
  float g = 0.f;
  for (int e = 0; e < D_; e++) g += hss[e]*glu2_w[t*D_ + e];
  g2[(size_t)b*D_ + t] = g;
}

// ---------------- beta[b,l] (parallel over (b,l)) ----------------
__global__ __launch_bounds__(128) void k_beta(
    const float* __restrict__ hidden, const int* __restrict__ mask,
    const float* __restrict__ pose, const float* __restrict__ w1s,
    const float* __restrict__ w2s, const float* __restrict__ glu1wT,
    const float* __restrict__ glu1b, const float* __restrict__ g2,
    float* __restrict__ betaW)
{
  __shared__ float hrow[128], prow[128], nh[128], red[128];
  int l = blockIdx.x, b = blockIdx.y, t = threadIdx.x;
  hrow[t] = hidden[((size_t)b*L_ + l)*128 + t];
  prow[t] = pose[l*128 + t];
  __syncthreads();
  float acc = 0.f;
  for (int e = 0; e < 128; e++) acc += prow[e]*w1s[e*128 + t];
  for (int e = 0; e < 128; e++) acc += hrow[e]*w1s[(128+e)*128 + t];
  nh[t] = tanhf(acc);
  __syncthreads();
  float a2 = 0.f;
  for (int e = 0; e < 128; e++) a2 += nh[e]*glu1wT[e*128 + t];
  float ns = sigm_(a2 + glu1b[t] + g2[(size_t)b*128 + t]);
  red[t] = ns * w2s[t];
  __syncthreads();
  for (int off = 64; off >= 1; off >>= 1){
    if (t < off) red[t] += red[t+off];
    __syncthreads();
  }
  if (t == 0) betaW[b*L_ + l] = red[0] * (float)mask[b*L_ + l];
}

// ---------------- select = sum_l beta*hidden; norms ----------------
__global__ __launch_bounds__(128) void k_selnorm(
    const float* __restrict__ hidden, const float* __restrict__ betaW,
    float* __restrict__ select, float* __restrict__ norms)
{
  __shared__ float bet[56];
  __shared__ float red[128];
  int b = blockIdx.x, t = threadIdx.x;
  if (t < L_) bet[t] = betaW[b*L_ + t];
  __syncthreads();
  float sel = 0.f;
  for (int l = 0; l < L_; l++) sel += bet[l]*hidden[((size_t)b*L_ + l)*128 + t];
  select[(size_t)b*128 + t] = sel;
  red[t] = sel*sel + 1e-6f;
  __syncthreads();
  for (int off=64; off>=1; off>>=1){ if (t<off) red[t]+=red[t+off]; __syncthreads(); }
  if (t==0) norms[b] = sqrtf(red[0]);
}

// ---------------- cosine softmax + top-9 + neighbor mix (writes bf16 sel2b) ----------------
__global__ __launch_bounds__(128) void k_topk(const float* __restrict__ select,
                                              const float* __restrict__ norms,
                                              short* __restrict__ select2b){
  __shared__ float p[B_];
  __shared__ float red[128];
  __shared__ float tv[NBR_];
  __shared__ int   ti[NBR_];
  int b = blockIdx.x, t = threadIdx.x;
  float dot = 0.f;
  for (int d = 0; d < D_; d++) dot += select[(size_t)b*D_ + d]*select[(size_t)t*D_ + d];
  float logit = dot / (norms[b]*norms[t]);
  red[t] = logit; __syncthreads();
  for (int off = 64; off >= 1; off >>= 1){
    if (t < off) red[t] = fmaxf(red[t], red[t + off]);
    __syncthreads();
  }
  float mx = red[0]; __syncthreads();
  float e_ = expf(logit - mx);
  red[t] = e_; __syncthreads();
  for (int off = 64; off >= 1; off >>= 1){
    if (t < off) red[t] += red[t + off];
    __syncthreads();
  }
  p[t] = e_ / red[0];
  __syncthreads();
  if (t == 0){
    unsigned long long used0 = 0ull, used1 = 0ull;
    for (int k = 0; k < NBR_; k++){
      float best = -INFINITY; int bi = 0;
      for (int j = 0; j < B_; j++){
        bool u = (j < 64) ? ((used0 >> j) & 1ull) : ((used1 >> (j-64)) & 1ull);
        if (!u && p[j] > best){ best = p[j]; bi = j; }
      }
      if (bi < 64) used0 |= 1ull << bi; else used1 |= 1ull << (bi-64);
      tv[k] = best; ti[k] = bi;
    }
    float mx2 = -INFINITY;
    for (int k = 0; k < NBR_; k++) mx2 = fmaxf(mx2, tv[k]);
    float s2 = 0.f;
    for (int k = 0; k < NBR_; k++){ tv[k] = expf(tv[k]-mx2); s2 += tv[k]; }
    for (int k = 0; k < NBR_; k++) tv[k] /= s2;
  }
  __syncthreads();
  float nb = 0.f;
#pragma unroll
  for (int k = 0; k < NBR_; k++) nb += tv[k]*select[(size_t)ti[k]*D_ + t];
  select2b[(size_t)b*D_ + t] = f2b(select[(size_t)b*D_ + t] + nb);
}

// ---------------- MFMA scores = sel2 @ emb[1:].T (no LDS) ----------------
__global__ __launch_bounds__(256) void k_scores(
    const short* __restrict__ sel2b, const float* __restrict__ emb,
    float* __restrict__ scores)
{
  const int tid = threadIdx.x;
  const int lane = tid & 63, wave = tid >> 6;
  const int quad = lane >> 4, l16 = lane & 15;
  int n = blockIdx.x*64 + wave*16 + l16;
  bool nvalid = (n < NSC_);
  const float* embrow = emb + (size_t)(1 + (nvalid ? n : 0))*128;
  f32x4 acc[8];
#pragma unroll
  for (int i=0;i<8;i++) acc[i] = zero4();
  for (int kc = 0; kc < 4; kc++){
    int k = kc*32 + quad*8;
    float4 f0 = *(const float4*)(embrow + k);
    float4 f1 = *(const float4*)(embrow + k + 4);
    bf16x8 bb = cvt8(f0, f1);
#pragma unroll
    for (int rt = 0; rt < 8; rt++){
      bf16x8 a = *(const bf16x8*)&sel2b[(rt*16 + l16)*128 + k];
      acc[rt] = mfma_bf16(a, bb, acc[rt]);
    }
  }
  if (nvalid){
#pragma unroll
    for (int rt = 0; rt < 8; rt++)
#pragma unroll
      for (int r = 0; r < 4; r++){
        int brow = rt*16 + quad*4 + r;
        scores[(size_t)brow*NSC_ + n] = acc[rt][r];
      }
  }
}

// ---------------- launcher ----------------
extern "C" void kernel_launch(void* const* d_in, const int* in_sizes, int n_in,
                              void* d_out, int out_size, void* d_ws, size_t ws_size,
                              hipStream_t stream) {
  (void)in_sizes; (void)n_in; (void)out_size; (void)ws_size;
  const int*   inputs  = (const int*)  d_in[0];
  const int*   adj     = (const int*)  d_in[1];
  const int*   mask    = (const int*)  d_in[2];
  const int*   item    = (const int*)  d_in[3];
  const int*   adj_all = (const int*)  d_in[5];
  const float* num_w   = (const float*)d_in[6];
  const float* emb     = (const float*)d_in[7];
  const float* pose    = (const float*)d_in[8];
  const float* a_local = (const float*)d_in[9];
  const float* gw1     = (const float*)d_in[10];
  const float* gw2     = (const float*)d_in[11];
  const float* gw3     = (const float*)d_in[12];
  const float* w1      = (const float*)d_in[13];
  const float* w2      = (const float*)d_in[14];
  const float* glu1w   = (const float*)d_in[15];
  const float* glu1b   = (const float*)d_in[16];
  const float* glu2w   = (const float*)d_in[17];
  float* out = (float*)d_out;

  // workspace layout (float units)
  float* W     = (float*)d_ws;
  float* hl    = W;                    // 819200
  float* hg    = W + 819200;           // 819200
  float* e0p   = W + 1638400;          // 819200
  float* e1p   = W + 2457600;          // 6553600
  float* sess  = W + 9011200;          // 16384
  float* g2    = W + 9027584;          // 16384
  float* sel   = W + 9043968;          // 16384
  short* sel2b = (short*)(W + 9060352);// 16384 shorts (reuse old sel2 slot)
  float* norms = W + 9076736;          // 256
  float* n1w   = W + 9076992;          // 51200
  float* n2w   = W + 9128192;          // 409600
  float* betaW = W + 9537792;          // 6400
  float* w1T   = W + 9544192;          // 32768 (2 hops)
  float* glu1wT= W + 9576960;          // 16384
  short* w3Tb  = (short*)(W + 9593344);// 2*128*264 shorts
  int*   n1i   = (int*)(W + 9627136);  // 51200
  int*   n2i   = n1i + 51200;          // 409600
  int*   pr    = n2i + 409600;         // 128
  int*   pc    = pr + 128;             // 50

  // Bsess (2 hops x 128 b x 128 d x 128 e, bf16 = 8 MB) parked in the scores
  // region of d_out (offset 819712 floats, 16B aligned); fully overwritten by
  // k_scores at the end of every call.
  short* BsessG = (short*)(out + 819712);

  k_prep<<<448, 256, 0, stream>>>(gw1, gw3, glu1w, w1T, glu1wT, w3Tb);
  k_sess<<<B_, D_, 0, stream>>>(item, mask, emb, sess);
  k_bsess<<<256, 256, 0, stream>>>(w1T, sess, BsessG);
  k_local<<<dim3(2, B_), 256, 0, stream>>>(inputs, emb, adj, a_local, hl);

  k_sample<<<(B_*L_*S_ + 255)/256, 256, 0, stream>>>(inputs, adj_all, num_w, B_*L_*S_, n1i, n1w);
  k_sample<<<(B_*L_*S_*S_ + 255)/256, 256, 0, stream>>>(n1i, adj_all, num_w, B_*L_*S_*S_, n2i, n2w);

  // hop0 i=0: self=emb[inputs], neigh=emb[n1i] -> e0p   (rpb=400)
  k_att <<<dim3(4, B_),  256, 0, stream>>>(emb, nullptr, n1i, n1w, BsessG, gw1, gw2, e0p, 400);
  k_gout<<<100, 256, 0, stream>>>(emb, nullptr, inputs, w3Tb, e0p);
  // hop0 i=1: self=emb[n1i], neigh=emb[n2i] -> e1p      (rpb=3200)
  k_att <<<dim3(25, B_), 256, 0, stream>>>(emb, nullptr, n2i, n2w, BsessG, gw1, gw2, e1p, 3200);
  k_gout<<<800, 256, 0, stream>>>(emb, nullptr, n1i, w3Tb, e1p);
  // hop1: self=e0p, neigh=e1p -> hg                     (rpb=400, weights[1])
  k_att <<<dim3(4, B_),  256, 0, stream>>>(emb, e1p, nullptr, n1w, BsessG + (size_t)128*16384,
                                           gw1 + 129*128, gw2 + 128, hg, 400);
  k_gout<<<100, 256, 0, stream>>>(emb, e0p, nullptr, w3Tb + 128*264, hg);

  k_addout<<<(B_*L_*D_ + 1 + 255)/256, 256, 0, stream>>>(hl, hg, out);

  k_perms<<<1, 128, 0, stream>>>(pr, pc);
  k_ssl<<<B_, 128, 0, stream>>>(hl, hg, pr, pc, out + B_*L_*D_);

  k_hs<<<B_, D_, 0, stream>>>(out, mask, glu2w, g2);
  k_beta<<<dim3(L_, B_), 128, 0, stream>>>(out, mask, pose, w1, w2, glu1wT, glu1b, g2, betaW);
  k_selnorm<<<B_, 128, 0, stream>>>(out, betaW, sel, norms);
  k_topk<<<B_, 128, 0, stream>>>(sel, norms, sel2b);
  k_scores<<<(NSC_ + 63)/64, 256, 0, stream>>>(sel2b, emb, out + B_*L_*D_ + 1);
}

// Round 4
// 506.564 us; speedup vs baseline: 3.2848x; 1.1575x over previous
//
#include <hip/hip_runtime.h>
#include <stdint.h>

// ---------------- constants ----------------
namespace {
constexpr int B_ = 128;
constexpr int L_ = 50;
constexpr int D_ = 128;
constexpr int S_ = 8;
constexpr int NSC_ = 99999;       // NUM_NODE-1
constexpr int NBR_ = 9;
}
#define LEAKY_ 0.2f
#define BETA_ 0.005f

typedef __attribute__((ext_vector_type(8))) __bf16 bf16x8;
typedef __attribute__((ext_vector_type(4))) float f32x4;

__device__ __forceinline__ float leaky_(float x){ return x >= 0.f ? x : LEAKY_*x; }
__device__ __forceinline__ float sigm_(float x){ return 1.f/(1.f+expf(-x)); }

__device__ __forceinline__ short f2b(float f){
  uint32_t u = __float_as_uint(f);
  u += 0x7fffu + ((u >> 16) & 1u);
  return (short)(u >> 16);
}
__device__ __forceinline__ float b2f(short s){
  return __uint_as_float(((uint32_t)(uint16_t)s) << 16);
}
__device__ __forceinline__ f32x4 zero4(){ f32x4 z = {0.f,0.f,0.f,0.f}; return z; }
__device__ __forceinline__ bf16x8 cvt8(float4 a, float4 b){
  union { short s[8]; bf16x8 v; } u;
  u.s[0]=f2b(a.x); u.s[1]=f2b(a.y); u.s[2]=f2b(a.z); u.s[3]=f2b(a.w);
  u.s[4]=f2b(b.x); u.s[5]=f2b(b.y); u.s[6]=f2b(b.z); u.s[7]=f2b(b.w);
  return u.v;
}
__device__ __forceinline__ f32x4 mfma_bf16(bf16x8 a, bf16x8 b, f32x4 c){
  return __builtin_amdgcn_mfma_f32_16x16x32_bf16(a, b, c, 0, 0, 0);
}

// ---------------- threefry2x32 (JAX-compatible) ----------------
__device__ __forceinline__ void tf2x32(uint32_t k0, uint32_t k1, uint32_t c0, uint32_t c1,
                                       uint32_t* o0, uint32_t* o1){
  uint32_t ks2 = k0 ^ k1 ^ 0x1BD11BDAu;
  uint32_t x0 = c0 + k0, x1 = c1 + k1;
#define RND_(r) { x0 += x1; x1 = (x1<<(r))|(x1>>(32-(r))); x1 ^= x0; }
  RND_(13) RND_(15) RND_(26) RND_(6)   x0 += k1;  x1 += ks2 + 1u;
  RND_(17) RND_(29) RND_(16) RND_(24)  x0 += ks2; x1 += k0  + 2u;
  RND_(13) RND_(15) RND_(26) RND_(6)   x0 += k0;  x1 += k1  + 3u;
  RND_(17) RND_(29) RND_(16) RND_(24)  x0 += k1;  x1 += ks2 + 4u;
  RND_(13) RND_(15) RND_(26) RND_(6)   x0 += ks2; x1 += k0  + 5u;
#undef RND_
  *o0 = x0; *o1 = x1;
}

// ---------------- fused prep: embB + weight transposes + sess ----------------
// blocks 0..3124: embB (bf16 copy of embedding, 4096 elts/block)
// blocks 3125..3572: w1T/glu1wT/w3T prep
// blocks 3573..3700: sess
__global__ __launch_bounds__(256) void k_prep_all(
    const float* __restrict__ emb, const int* __restrict__ item,
    const int* __restrict__ mask, const float* __restrict__ gw1,
    const float* __restrict__ gw3, const float* __restrict__ glu1w,
    short* __restrict__ embB, float* __restrict__ w1T,
    float* __restrict__ glu1wT, short* __restrict__ w3T,
    float* __restrict__ sess)
{
  int blk = blockIdx.x, tid = threadIdx.x;
  if (blk < 3125){
    size_t base = (size_t)blk*4096 + (size_t)tid*16;
    float4 f0 = *(const float4*)(emb + base);
    float4 f1 = *(const float4*)(emb + base + 4);
    float4 f2 = *(const float4*)(emb + base + 8);
    float4 f3 = *(const float4*)(emb + base + 12);
    short4 s0, s1, s2, s3;
    s0.x=f2b(f0.x); s0.y=f2b(f0.y); s0.z=f2b(f0.z); s0.w=f2b(f0.w);
    s1.x=f2b(f1.x); s1.y=f2b(f1.y); s1.z=f2b(f1.z); s1.w=f2b(f1.w);
    s2.x=f2b(f2.x); s2.y=f2b(f2.y); s2.z=f2b(f2.z); s2.w=f2b(f2.w);
    s3.x=f2b(f3.x); s3.y=f2b(f3.y); s3.z=f2b(f3.z); s3.w=f2b(f3.w);
    *(short4*)(embB + base)      = s0;
    *(short4*)(embB + base + 4)  = s1;
    *(short4*)(embB + base + 8)  = s2;
    *(short4*)(embB + base + 12) = s3;
  } else if (blk < 3573){
    int o = (blk - 3125)*256 + tid;
    if (o < 32768){
      int hop = o >> 14, r = o & 16383;
      int d = r >> 7, e = r & 127;
      w1T[o] = gw1[hop*(129*128) + e*128 + d];
    } else if (o < 49152){
      int o2 = o - 32768;
      int e = o2 >> 7, t = o2 & 127;
      glu1wT[o2] = glu1w[t*128 + e];
    } else if (o < 114688){
      int o3 = o - 49152;
      int hop = o3 >> 15, r = o3 & 32767;
      int nn = r >> 8, k = r & 255;
      w3T[hop*(128*264) + nn*264 + k] = f2b(gw3[hop*(256*128) + k*128 + nn]);
    }
  } else {
    int b = blk - 3573;
    if (tid < 128){
      float acc = 0.f, ms = 0.f;
      for (int l = 0; l < L_; l++){
        float mk = (float)mask[b*L_ + l];
        ms += mk;
        acc += mk * emb[(size_t)item[b*L_ + l]*D_ + tid];
      }
      sess[(size_t)b*D_ + tid] = acc / ms;
    }
  }
}

// ---------------- fused stage2: Bsess + 2-hop sampling ----------------
// blocks 0..255: Bsess[hop][b][d][e] = bf16(w1T[hop][d][e]*sess[b][e])
// blocks 256..455: both hops of neighbor sampling
__global__ __launch_bounds__(256) void k_stage2(
    const float* __restrict__ w1T, const float* __restrict__ sess,
    const int* __restrict__ inputs, const int* __restrict__ adj_all,
    const float* __restrict__ num_w,
    short* __restrict__ Bsess, int* __restrict__ n1i, float* __restrict__ n1w,
    int* __restrict__ n2i, float* __restrict__ n2w)
{
  int blk = blockIdx.x, tid = threadIdx.x;
  if (blk < 256){
    int hop = blk >> 7, b = blk & 127;
    const float* wt = w1T + hop*16384;
    short* outp = Bsess + ((size_t)hop*128 + b)*16384;
    __shared__ float sessS[128];
    if (tid < 128) sessS[tid] = sess[b*128 + tid];
    __syncthreads();
    for (int it = 0; it < 64; it++){
      int u = it*256 + tid;
      outp[u] = f2b(wt[u] * sessS[u & 127]);
    }
  } else {
    int p = (blk - 256)*256 + tid;   // p < 51200
    int base = inputs[p >> 3];
    int off  = base*S_ + (p & 7);
    int i1 = adj_all[off];
    n1i[p] = i1;
    n1w[p] = num_w[off];
#pragma unroll
    for (int j = 0; j < 8; j++){
      n2i[(size_t)p*8 + j] = adj_all[i1*8 + j];
      n2w[(size_t)p*8 + j] = num_w[i1*8 + j];
    }
  }
}

// ---------------- local GAT aggregation (bf16 table, split i over 2 blocks/b) --------
__global__ __launch_bounds__(256) void k_local(const int* __restrict__ inputs,
                                               const short* __restrict__ embB,
                                               const int* __restrict__ adj,
                                               const float* __restrict__ a_local,
                                               float* __restrict__ hl){
  __shared__ float hs[L_*129];
  __shared__ float att[25*52];
  __shared__ float al[4*132];
  __shared__ int idxs[L_];
  int b = blockIdx.y, half = blockIdx.x, tid = threadIdx.x;
  int i0 = half*25;
  if (tid < L_) idxs[tid] = inputs[b*L_ + tid];
  __syncthreads();
  for (int u = tid; u < L_*16; u += 256){
    int i = u >> 4, c = u & 15;
    union { bf16x8 v; short sh[8]; } w;
    w.v = *(const bf16x8*)&embB[(size_t)idxs[i]*128 + c*8];
#pragma unroll
    for (int j = 0; j < 8; j++) hs[i*129 + c*8 + j] = b2f(w.sh[j]);
  }
  for (int e = tid; e < 4*D_; e += 256) al[(e>>7)*132 + (e&127)] = a_local[e];
  __syncthreads();
  for (int p = tid; p < 25*L_; p += 256){
    int il = p / L_, j = p % L_;
    int i = i0 + il;
    int k = adj[((size_t)b*L_ + i)*L_ + j];
    float v = -9e15f;
    if (k >= 1){
      const float* ak = &al[(k-1)*132];
      float acc = 0.f;
      for (int d = 0; d < D_; d++) acc += hs[i*129+d]*hs[j*129+d]*ak[d];
      v = leaky_(acc);
    }
    att[il*52 + j] = v;
  }
  __syncthreads();
  if (tid < 25){
    int il = tid;
    float mx = -INFINITY;
    for (int j = 0; j < L_; j++) mx = fmaxf(mx, att[il*52+j]);
    float sm = 0.f;
    for (int j = 0; j < L_; j++){ float e_ = expf(att[il*52+j] - mx); att[il*52+j] = e_; sm += e_; }
    float inv = 1.f/sm;
    for (int j = 0; j < L_; j++) att[il*52+j] *= inv;
  }
  __syncthreads();
  for (int q = tid; q < 25*D_; q += 256){
    int il = q >> 7, d = q & 127;
    float acc = 0.f;
    for (int j = 0; j < L_; j++) acc += att[il*52+j]*hs[j*129+d];
    hl[((size_t)b*L_ + i0 + il)*D_ + d] = acc;
  }
}

// ---------------- MFMA global-agg attention ----------------
__global__ __launch_bounds__(256, 4) void k_att(
    const short* __restrict__ embB, const float* __restrict__ dense,
    const int* __restrict__ nidx, const float* __restrict__ nw,
    const short* __restrict__ Bsess,
    const float* __restrict__ w1g, const float* __restrict__ w2g,
    float* __restrict__ outn, int rpb)
{
  __shared__ __align__(16) short As[128*136];
  __shared__ float w1lS[128], w2S[128], nwsS[128], logitsS[128], alphaS[128];
  const int tid = threadIdx.x;
  const int b = blockIdx.y;
  const int r0 = blockIdx.x * 128;
  if (tid < 128){
    w1lS[tid]  = w1g[128*128 + tid];
    w2S[tid]   = w2g[tid];
    int rr = min(r0 + tid, rpb - 1);
    nwsS[tid]  = nw[(size_t)b*rpb + rr];
  }
  if (dense){
    for (int it = 0; it < 16; it++){
      int u = it*256 + tid;
      int lr = u >> 5, c = u & 31;
      int rr = min(r0 + lr, rpb - 1);
      const float* src = dense + ((size_t)b*rpb + rr)*128;
      float4 v = *(const float4*)(src + c*4);
      short4 s4; s4.x=f2b(v.x); s4.y=f2b(v.y); s4.z=f2b(v.z); s4.w=f2b(v.w);
      *(short4*)&As[lr*136 + c*4] = s4;
    }
  } else {
    for (int it = 0; it < 8; it++){
      int u = it*256 + tid;
      int lr = u >> 4, c = u & 15;
      int rr = min(r0 + lr, rpb - 1);
      bf16x8 v = *(const bf16x8*)&embB[(size_t)nidx[(size_t)b*rpb + rr]*128 + c*8];
      *(bf16x8*)&As[lr*136 + c*8] = v;
    }
  }
  __syncthreads();
  const int lane = tid & 63, wave = tid >> 6;
  const int quad = lane >> 4, l16 = lane & 15;
  const int wr0 = wave * 32;
  const short* Bb = Bsess + (size_t)b*16384;
  f32x4 acc[2][8];
#pragma unroll
  for (int i=0;i<2;i++)
#pragma unroll
    for (int j=0;j<8;j++) acc[i][j] = zero4();
  for (int kc = 0; kc < 4; kc++){
    int k = kc*32 + quad*8;
    bf16x8 a0 = *(const bf16x8*)&As[(wr0 + l16)*136 + k];
    bf16x8 a1 = *(const bf16x8*)&As[(wr0 + 16 + l16)*136 + k];
    bf16x8 bb[8];
#pragma unroll
    for (int nt = 0; nt < 8; nt++)
      bb[nt] = *(const bf16x8*)&Bb[(size_t)(nt*16 + l16)*128 + k];
#pragma unroll
    for (int nt = 0; nt < 8; nt++){
      acc[0][nt] = mfma_bf16(a0, bb[nt], acc[0][nt]);
      acc[1][nt] = mfma_bf16(a1, bb[nt], acc[1][nt]);
    }
  }
#pragma unroll
  for (int rt = 0; rt < 2; rt++){
#pragma unroll
    for (int r = 0; r < 4; r++){
      int rowl = wr0 + rt*16 + quad*4 + r;
      float nwv = nwsS[rowl];
      float c = 0.f;
#pragma unroll
      for (int nt = 0; nt < 8; nt++){
        int col = nt*16 + l16;
        float v = acc[rt][nt][r] + nwv * w1lS[col];
        c += leaky_(v) * w2S[col];
      }
      c += __shfl_xor(c, 1, 64);
      c += __shfl_xor(c, 2, 64);
      c += __shfl_xor(c, 4, 64);
      c += __shfl_xor(c, 8, 64);
      if (l16 == 0) logitsS[rowl] = c;
    }
  }
  __syncthreads();
  if (tid < 16){
    float mx = -INFINITY;
    for (int s = 0; s < 8; s++) mx = fmaxf(mx, logitsS[tid*8+s]);
    float sm = 0.f; float ev[8];
    for (int s = 0; s < 8; s++){ ev[s] = expf(logitsS[tid*8+s]-mx); sm += ev[s]; }
    for (int s = 0; s < 8; s++) alphaS[tid*8+s] = ev[s]/sm;
  }
  __syncthreads();
  {
    int mg = tid >> 4;
    int dc = tid & 15;
    float o[8];
#pragma unroll
    for (int j = 0; j < 8; j++) o[j] = 0.f;
#pragma unroll
    for (int s = 0; s < 8; s++){
      float al = alphaS[mg*8+s];
      union { bf16x8 v; short sh[8]; } u;
      u.v = *(const bf16x8*)&As[(mg*8+s)*136 + dc*8];
#pragma unroll
      for (int j = 0; j < 8; j++) o[j] += al * b2f(u.sh[j]);
    }
    if (r0 + mg*8 < rpb){
      int m = (r0 >> 3) + mg;
      float* dst = outn + ((size_t)b*(rpb>>3) + m)*128 + dc*8;
      *(float4*)dst       = make_float4(o[0],o[1],o[2],o[3]);
      *(float4*)(dst + 4) = make_float4(o[4],o[5],o[6],o[7]);
    }
  }
}

// ---------------- MFMA global-agg output: inout = relu([self||neigh]@w3) ----------------
__global__ __launch_bounds__(256) void k_gout(
    const short* __restrict__ embB, const float* __restrict__ self_dense,
    const int* __restrict__ self_idx, const short* __restrict__ w3T,
    float* __restrict__ inout)
{
  const int tid = threadIdx.x;
  const int lane = tid & 63, wave = tid >> 6;
  const int quad = lane >> 4, l16 = lane & 15;
  const int rbase = blockIdx.x*64 + wave*16;
  const int row = rbase + l16;
  const float* selfp = self_dense ? self_dense + (size_t)row*128 : nullptr;
  const short* selfB = self_dense ? nullptr : embB + (size_t)self_idx[row]*128;
  const float* neighp = inout + (size_t)row*128;
  f32x4 acc[8];
#pragma unroll
  for (int i=0;i<8;i++) acc[i] = zero4();
  for (int kc = 0; kc < 4; kc++){
    int k = kc*32 + quad*8;
    bf16x8 a;
    if (self_dense){
      float4 f0 = *(const float4*)(selfp + k);
      float4 f1 = *(const float4*)(selfp + k + 4);
      a = cvt8(f0, f1);
    } else {
      a = *(const bf16x8*)&selfB[k];
    }
#pragma unroll
    for (int nt = 0; nt < 8; nt++){
      bf16x8 bb = *(const bf16x8*)&w3T[(size_t)(nt*16 + l16)*264 + k];
      acc[nt] = mfma_bf16(a, bb, acc[nt]);
    }
  }
  for (int kc = 4; kc < 8; kc++){
    int k = kc*32 + quad*8;
    float4 f0 = *(const float4*)(neighp + k - 128);
    float4 f1 = *(const float4*)(neighp + k - 124);
    bf16x8 a = cvt8(f0, f1);
#pragma unroll
    for (int nt = 0; nt < 8; nt++){
      bf16x8 bb = *(const bf16x8*)&w3T[(size_t)(nt*16 + l16)*264 + k];
      acc[nt] = mfma_bf16(a, bb, acc[nt]);
    }
  }
#pragma unroll
  for (int nt = 0; nt < 8; nt++)
#pragma unroll
    for (int r = 0; r < 4; r++){
      int orow = rbase + quad*4 + r;
      inout[(size_t)orow*128 + nt*16 + l16] = fmaxf(acc[nt][r], 0.f);
    }
}

// ---------------- fused: perms + SSL partial + out = hl + hg ----------------
__global__ __launch_bounds__(128) void k_ssl_add(
    const float* __restrict__ hl, const float* __restrict__ hg,
    float* __restrict__ out, float* __restrict__ wsLoss)
{
  __shared__ uint32_t keys[128];
  __shared__ float red[128];
  __shared__ int pcS[50];
  __shared__ int prbS;
  int b = blockIdx.x, tid = threadIdx.x;
  uint32_t kr0, kr1, kc0, kc1, sk0, sk1, o0, o1;
  tf2x32(0u, 42u, 0u, 0u, &kr0, &kr1);
  tf2x32(0u, 42u, 0u, 1u, &kc0, &kc1);
  tf2x32(kr0, kr1, 0u, 1u, &sk0, &sk1);
  tf2x32(sk0, sk1, 0u, (uint32_t)tid, &o0, &o1);
  keys[tid] = o0 ^ o1;
  __syncthreads();
  {
    uint32_t mk = keys[tid];
    int rank = 0;
    for (int j = 0; j < 128; j++){
      uint32_t kj = keys[j];
      rank += (kj < mk) || (kj == mk && j < tid);
    }
    if (rank == b) prbS = tid;
  }
  __syncthreads();
  tf2x32(kc0, kc1, 0u, 1u, &sk0, &sk1);
  if (tid < 50){
    tf2x32(sk0, sk1, 0u, (uint32_t)tid, &o0, &o1);
    keys[tid] = o0 ^ o1;
  }
  __syncthreads();
  if (tid < 50){
    uint32_t mk = keys[tid];
    int rank = 0;
    for (int j = 0; j < 50; j++){
      uint32_t kj = keys[j];
      rank += (kj < mk) || (kj == mk && j < tid);
    }
    pcS[rank] = tid;
  }
  __syncthreads();
  int prb = prbS, d = tid;
  float pos = 0.f, neg = 0.f;
  for (int l = 0; l < L_; l++){
    size_t off = ((size_t)b*L_ + l)*D_ + d;
    float hlv = hl[off], hgv = hg[off];
    out[off] = hlv + hgv;
    pos += hlv * hgv;
    neg += hgv * hl[((size_t)prb*L_ + pcS[l])*D_ + d];
  }
  red[d] = -logf(1e-8f + sigm_(pos)) - logf(1e-8f + 1.f - sigm_(neg));
  __syncthreads();
  for (int off = 64; off >= 1; off >>= 1){
    if (d < off) red[d] += red[d + off];
    __syncthreads();
  }
  if (d == 0) wsLoss[b] = red[0];
}

// ---------------- hs -> g2; block 0 also finalizes the loss ----------------
__global__ __launch_bounds__(128) void k_hs(
    const float* __restrict__ hidden, const int* __restrict__ mask,
    const float* __restrict__ glu2_w, const float* __restrict__ wsLoss,
    float* __restrict__ g2, float* __restrict__ out_loss)
{
  __shared__ float hss[D_];
  __shared__ float lred[128];
  int b = blockIdx.x, t = threadIdx.x;
  float acc = 0.f, ms = 0.f;
  for (int l = 0; l < L_; l++){
    float mk = (float)mask[b*L_ + l];
    ms += mk;
    acc += mk * hidden[((size_t)b*L_ + l)*D_ + t];
  }
  hss[t] = acc / ms;
  lred[t] = (b == 0) ? wsLoss[t] : 0.f;
  __syncthreads();
  float g = 0.f;
  for (int e = 0; e < D_; e++) g += hss[e]*glu2_w[t*D_ + e];
  g2[(size_t)b*D_ + t] = g;
  for (int off = 64; off >= 1; off >>= 1){
    if (t < off) lred[t] += lred[t + off];
    __syncthreads();
  }
  if (b == 0 && t == 0) out_loss[0] = BETA_ * lred[0];
}

// ---------------- beta[b,l] ----------------
__global__ __launch_bounds__(128) void k_beta(
    const float* __restrict__ hidden, const int* __restrict__ mask,
    const float* __restrict__ pose, const float* __restrict__ w1s,
    const float* __restrict__ w2s, const float* __restrict__ glu1wT,
    const float* __restrict__ glu1b, const float* __restrict__ g2,
    float* __restrict__ betaW)
{
  __shared__ float hrow[128], prow[128], nh[128], red[128];
  int l = blockIdx.x, b = blockIdx.y, t = threadIdx.x;
  hrow[t] = hidden[((size_t)b*L_ + l)*128 + t];
  prow[t] = pose[l*128 + t];
  __syncthreads();
  float acc = 0.f;
  for (int e = 0; e < 128; e++) acc += prow[e]*w1s[e*128 + t];
  for (int e = 0; e < 128; e++) acc += hrow[e]*w1s[(128+e)*128 + t];
  nh[t] = tanhf(acc);
  __syncthreads();
  float a2 = 0.f;
  for (int e = 0; e < 128; e++) a2 += nh[e]*glu1wT[e*128 + t];
  float ns = sigm_(a2 + glu1b[t] + g2[(size_t)b*128 + t]);
  red[t] = ns * w2s[t];
  __syncthreads();
  for (int off = 64; off >= 1; off >>= 1){
    if (t < off) red[t] += red[t+off];
    __syncthreads();
  }
  if (t == 0) betaW[b*L_ + l] = red[0] * (float)mask[b*L_ + l];
}

// ---------------- select = sum_l beta*hidden; norms ----------------
__global__ __launch_bounds__(128) void k_selnorm(
    const float* __restrict__ hidden, const float* __restrict__ betaW,
    float* __restrict__ select, float* __restrict__ norms)
{
  __shared__ float bet[56];
  __shared__ float red[128];
  int b = blockIdx.x, t = threadIdx.x;
  if (t < L_) bet[t] = betaW[b*L_ + t];
  __syncthreads();
  float sel = 0.f;
  for (int l = 0; l < L_; l++) sel += bet[l]*hidden[((size_t)b*L_ + l)*128 + t];
  select[(size_t)b*128 + t] = sel;
  red[t] = sel*sel + 1e-6f;
  __syncthreads();
  for (int off=64; off>=1; off>>=1){ if (t<off) red[t]+=red[t+off]; __syncthreads(); }
  if (t==0) norms[b] = sqrtf(red[0]);
}

// ---------------- cosine softmax + top-9 + neighbor mix ----------------
__global__ __launch_bounds__(128) void k_topk(const float* __restrict__ select,
                                              const float* __restrict__ norms,
                                              short* __restrict__ select2b){
  __shared__ float p[B_];
  __shared__ float red[128];
  __shared__ float tv[NBR_];
  __shared__ int   ti[NBR_];
  int b = blockIdx.x, t = threadIdx.x;
  float dot = 0.f;
  for (int d = 0; d < D_; d++) dot += select[(size_t)b*D_ + d]*select[(size_t)t*D_ + d];
  float logit = dot / (norms[b]*norms[t]);
  red[t] = logit; __syncthreads();
  for (int off = 64; off >= 1; off >>= 1){
    if (t < off) red[t] = fmaxf(red[t], red[t + off]);
    __syncthreads();
  }
  float mx = red[0]; __syncthreads();
  float e_ = expf(logit - mx);
  red[t] = e_; __syncthreads();
  for (int off = 64; off >= 1; off >>= 1){
    if (t < off) red[t] += red[t + off];
    __syncthreads();
  }
  p[t] = e_ / red[0];
  __syncthreads();
  if (t == 0){
    unsigned long long used0 = 0ull, used1 = 0ull;
    for (int k = 0; k < NBR_; k++){
      float best = -INFINITY; int bi = 0;
      for (int j = 0; j < B_; j++){
        bool u = (j < 64) ? ((used0 >> j) & 1ull) : ((used1 >> (j-64)) & 1ull);
        if (!u && p[j] > best){ best = p[j]; bi = j; }
      }
      if (bi < 64) used0 |= 1ull << bi; else used1 |= 1ull << (bi-64);
      tv[k] = best; ti[k] = bi;
    }
    float mx2 = -INFINITY;
    for (int k = 0; k < NBR_; k++) mx2 = fmaxf(mx2, tv[k]);
    float s2 = 0.f;
    for (int k = 0; k < NBR_; k++){ tv[k] = expf(tv[k]-mx2); s2 += tv[k]; }
    for (int k = 0; k < NBR_; k++) tv[k] /= s2;
  }
  __syncthreads();
  float nb = 0.f;
#pragma unroll
  for (int k = 0; k < NBR_; k++) nb += tv[k]*select[(size_t)ti[k]*D_ + t];
  select2b[(size_t)b*D_ + t] = f2b(select[(size_t)b*D_ + t] + nb);
}

// ---------------- MFMA scores = sel2 @ emb[1:].T (LDS-staged B) ----------------
__global__ __launch_bounds__(256) void k_scores(
    const short* __restrict__ sel2b, const float* __restrict__ emb,
    float* __restrict__ scores)
{
  __shared__ __align__(16) short Es[64*136];
  const int tid = threadIdx.x;
  const int n0 = blockIdx.x*64;
  for (int it = 0; it < 8; it++){
    int u = it*256 + tid;
    int lr = u >> 5, c = u & 31;
    int n = min(n0 + lr, NSC_ - 1);
    float4 v = *(const float4*)(emb + (size_t)(1 + n)*128 + c*4);
    short4 s4; s4.x=f2b(v.x); s4.y=f2b(v.y); s4.z=f2b(v.z); s4.w=f2b(v.w);
    *(short4*)&Es[lr*136 + c*4] = s4;
  }
  __syncthreads();
  const int lane = tid & 63, wave = tid >> 6;
  const int quad = lane >> 4, l16 = lane & 15;
  int n = n0 + wave*16 + l16;
  f32x4 acc[8];
#pragma unroll
  for (int i=0;i<8;i++) acc[i] = zero4();
  for (int kc = 0; kc < 4; kc++){
    int k = kc*32 + quad*8;
    bf16x8 bb = *(const bf16x8*)&Es[(wave*16 + l16)*136 + k];
#pragma unroll
    for (int rt = 0; rt < 8; rt++){
      bf16x8 a = *(const bf16x8*)&sel2b[(rt*16 + l16)*128 + k];
      acc[rt] = mfma_bf16(a, bb, acc[rt]);
    }
  }
  if (n < NSC_){
#pragma unroll
    for (int rt = 0; rt < 8; rt++)
#pragma unroll
      for (int r = 0; r < 4; r++){
        int brow = rt*16 + quad*4 + r;
        scores[(size_t)brow*NSC_ + n] = acc[rt][r];
      }
  }
}

// ---------------- launcher ----------------
extern "C" void kernel_launch(void* const* d_in, const int* in_sizes, int n_in,
                              void* d_out, int out_size, void* d_ws, size_t ws_size,
                              hipStream_t stream) {
  (void)in_sizes; (void)n_in; (void)out_size; (void)ws_size;
  const int*   inputs  = (const int*)  d_in[0];
  const int*   adj     = (const int*)  d_in[1];
  const int*   mask    = (const int*)  d_in[2];
  const int*   item    = (const int*)  d_in[3];
  const int*   adj_all = (const int*)  d_in[5];
  const float* num_w   = (const float*)d_in[6];
  const float* emb     = (const float*)d_in[7];
  const float* pose    = (const float*)d_in[8];
  const float* a_local = (const float*)d_in[9];
  const float* gw1     = (const float*)d_in[10];
  const float* gw2     = (const float*)d_in[11];
  const float* gw3     = (const float*)d_in[12];
  const float* w1      = (const float*)d_in[13];
  const float* w2      = (const float*)d_in[14];
  const float* glu1w   = (const float*)d_in[15];
  const float* glu1b   = (const float*)d_in[16];
  const float* glu2w   = (const float*)d_in[17];
  float* out = (float*)d_out;

  // workspace layout (float units)
  float* W     = (float*)d_ws;
  float* hl    = W;                    // 819200
  float* hg    = W + 819200;           // 819200
  float* e0p   = W + 1638400;          // 819200
  float* e1p   = W + 2457600;          // 6553600
  float* sess  = W + 9011200;          // 16384
  float* g2    = W + 9027584;          // 16384
  float* sel   = W + 9043968;          // 16384
  short* sel2b = (short*)(W + 9060352);// 16384 shorts
  float* norms = W + 9076736;          // 128
  float* wsLoss= W + 9076864;          // 128
  float* n1w   = W + 9076992;          // 51200
  float* n2w   = W + 9128192;          // 409600
  float* betaW = W + 9537792;          // 6400
  float* w1T   = W + 9544192;          // 32768 (2 hops)
  float* glu1wT= W + 9576960;          // 16384
  short* w3Tb  = (short*)(W + 9593344);// 2*128*264 shorts
  int*   n1i   = (int*)(W + 9627136);  // 51200
  int*   n2i   = n1i + 51200;          // 409600

  // d_out scratch (scores region, fully overwritten by k_scores at the end):
  // embB: bf16 embedding table, 12.8M shorts = 3,200,000 float-slots
  // Bsess: 2 hops x 128 b x 16384 bf16 = 2,097,152 float-slots
  short* embB   = (short*)(out + 819712);
  short* BsessG = (short*)(out + 819712 + 3200000);

  k_prep_all<<<3701, 256, 0, stream>>>(emb, item, mask, gw1, gw3, glu1w,
                                       embB, w1T, glu1wT, w3Tb, sess);
  k_stage2<<<456, 256, 0, stream>>>(w1T, sess, inputs, adj_all, num_w,
                                    BsessG, n1i, n1w, n2i, n2w);
  k_local<<<dim3(2, B_), 256, 0, stream>>>(inputs, embB, adj, a_local, hl);

  // hop0 i=0: self=embB[inputs], neigh=embB[n1i] -> e0p   (rpb=400)
  k_att <<<dim3(4, B_),  256, 0, stream>>>(embB, nullptr, n1i, n1w, BsessG, gw1, gw2, e0p, 400);
  k_gout<<<100, 256, 0, stream>>>(embB, nullptr, inputs, w3Tb, e0p);
  // hop0 i=1: self=embB[n1i], neigh=embB[n2i] -> e1p      (rpb=3200)
  k_att <<<dim3(25, B_), 256, 0, stream>>>(embB, nullptr, n2i, n2w, BsessG, gw1, gw2, e1p, 3200);
  k_gout<<<800, 256, 0, stream>>>(embB, nullptr, n1i, w3Tb, e1p);
  // hop1: self=e0p, neigh=e1p -> hg                       (rpb=400, weights[1])
  k_att <<<dim3(4, B_),  256, 0, stream>>>(embB, e1p, nullptr, n1w,
                                           BsessG + (size_t)128*16384,
                                           gw1 + 129*128, gw2 + 128, hg, 400);
  k_gout<<<100, 256, 0, stream>>>(embB, e0p, nullptr, w3Tb + 128*264, hg);

  k_ssl_add<<<B_, 128, 0, stream>>>(hl, hg, out, wsLoss);
  k_hs<<<B_, 128, 0, stream>>>(out, mask, glu2w, wsLoss, g2, out + B_*L_*D_);
  k_beta<<<dim3(L_, B_), 128, 0, stream>>>(out, mask, pose, w1, w2, glu1wT, glu1b, g2, betaW);
  k_selnorm<<<B_, 128, 0, stream>>>(out, betaW, sel, norms);
  k_topk<<<B_, 128, 0, stream>>>(sel, norms, sel2b);
  k_scores<<<(NSC_ + 63)/64, 256, 0, stream>>>(sel2b, emb, out + B_*L_*D_ + 1);
}